// Round 17
// baseline (304.848 us; speedup 1.0000x reference)
//
#include <hip/hip_runtime.h>
#include <hip/hip_bf16.h>
#include <math.h>

#define BB 8
#define CC 64
#define NN 500
#define TT 12
#define HH 4
#define FF 64
#define CT (CC*TT)      // 768
#define HF (HH*FF)      // 256
#define NBT (HH*TT)     // 48
#define NBHT (BB*NBT)   // 384
#define NROWS (BB*HH*TT*NN)  // 192000
#define NNODE (BB*NN)   // 4000
#define BSR 200         // k45 LDS row stride (ushorts)
#define KST 68          // k2 LDS B row stride (ushorts)

typedef unsigned short ushort_t;
typedef unsigned int uint_t;
typedef __attribute__((ext_vector_type(8))) short short8;
typedef __attribute__((ext_vector_type(4))) float floatx4;

static __device__ __forceinline__ ushort_t f2bf(float v) {
    __hip_bfloat16 h = __float2bfloat16(v);
    ushort_t u;
    __builtin_memcpy(&u, &h, 2);
    return u;
}

// pack two f32 -> packed bf16 (lo = a, hi = b), RNE (hw v_cvt_pk on gfx950)
static __device__ __forceinline__ uint_t pkbf(float a, float b) {
    __hip_bfloat162 h = __float22bfloat162_rn(make_float2(a, b));
    uint_t u;
    __builtin_memcpy(&u, &h, 4);
    return u;
}

// ---------------------------------------------------------------------------
// K016: merged setup + x-transpose.
// Blocks [0,32):    bitmask[512][16 dwords] of (adj+I)>0.
// Blocks [32,209):  p1/p2 folds, WmB=bf16(Wm), WgB=bf16(Wg), WtB=bf16(W^T).
// Blocks [209,465): transpose x [B,C,N,T] -> xT node-major.
// ---------------------------------------------------------------------------
__global__ __launch_bounds__(256) void k016_setup(const float* __restrict__ adj,
                                                  const float* __restrict__ W,
                                                  const float* __restrict__ a1,
                                                  const float* __restrict__ a2,
                                                  const float* __restrict__ Wm,
                                                  const float* __restrict__ Wg,
                                                  const float* __restrict__ x,
                                                  uint_t* __restrict__ maskbits,
                                                  float* __restrict__ p1,
                                                  float* __restrict__ p2,
                                                  ushort_t* __restrict__ WmB,
                                                  ushort_t* __restrict__ WgB,
                                                  ushort_t* __restrict__ WtB,
                                                  float* __restrict__ xT) {
    __shared__ float tile[16*776];   // used by the k6 path only
    int blk = blockIdx.x;
    if (blk < 32) {
        int idx = blk * 256 + threadIdx.x;   // < 512*16
        int n = idx >> 4, j = idx & 15;      // dword j covers m = j*32..+31
        uint_t v = 0;
        if (n < NN) {
            int m0 = j * 32;
            for (int i = 0; i < 32; ++i) {
                int m = m0 + i;
                bool p = (m < NN) && (adj[n*NN + m] > 0.f || m == n);
                v |= (p ? 1u : 0u) << i;
            }
        }
        maskbits[idx] = v;
        return;
    }
    if (blk < 209) {
        int idx = (blk - 32) * 256 + threadIdx.x;
        if (idx < HH*CC) {
            int h = idx / CC, c = idx % CC;
            float s1 = 0.f, s2 = 0.f;
            for (int f = 0; f < FF; ++f) {
                float w = W[(h*CC + c)*FF + f];
                s1 += w * a1[h*FF + f];
                s2 += w * a2[h*FF + f];
            }
            p1[idx] = s1; p2[idx] = s2;
        }
        int j = idx - HH*CC;
        if (j >= 0 && j < CC*3*CC) {          // WmB = bf16(Wm), [o][192]
            WmB[j] = f2bf(Wm[j]);
        }
        int j2 = idx - (HH*CC + CC*3*CC);
        if (j2 >= 0 && j2 < FF*HF) {
            WgB[j2] = f2bf(Wg[j2]);
        }
        int j3 = idx - (HH*CC + CC*3*CC + FF*HF);
        if (j3 >= 0 && j3 < HH*CC*FF) {       // WtB[h][f][c] = W[h][c][f]
            int h = j3 >> 12, rem = j3 & 4095;
            int f = rem >> 6, c = rem & 63;
            WtB[j3] = f2bf(W[h*4096 + c*64 + f]);
        }
        return;
    }
    // k6 body: blocks 209..464 -> xblk 0..255
    int xblk = blk - 209;
    int b  = xblk >> 5;
    int n0 = (xblk & 31) * 16;
    for (int idx = threadIdx.x; idx < CC*16*TT; idx += 256) {
        int c   = idx / (16*TT);
        int rem = idx % (16*TT);
        int nl  = rem / TT;
        int t   = rem % TT;
        int n   = n0 + nl;
        if (n < NN)
            tile[nl*776 + c*TT + t] = x[((b*CC + c)*NN + n)*TT + t];
    }
    __syncthreads();
    for (int idx = threadIdx.x; idx < 16*CT; idx += 256) {
        int nl = idx / CT;
        int j  = idx % CT;
        int n  = n0 + nl;
        if (n < NN)
            xT[(size_t)(b*NN + n)*CT + j] = tile[nl*776 + j];
    }
}

// ---------------------------------------------------------------------------
// K2: Wh via MFMA.  Block = 4 nodes; wave = head h.  (R14 form, frozen)
// ---------------------------------------------------------------------------
__global__ __launch_bounds__(256) void k2_wh_e(const float* __restrict__ hin,
                                               const ushort_t* __restrict__ WtB,
                                               const float* __restrict__ p1,
                                               const float* __restrict__ p2,
                                               ushort_t* __restrict__ Wh,
                                               float* __restrict__ e1,
                                               float* __restrict__ e2) {
    __shared__ float    hL[4][CT];        // 12288 B (fp32, for e-calc)
    __shared__ ushort_t Bs[4][TT*KST];    // 6528 B (bf16 [t][c] rows)
    int tid  = threadIdx.x;
    int wid  = tid >> 6;                  // wave = head h
    int lane = tid & 63;
    int quad = lane >> 4;
    int r    = lane & 15;
    int node0 = blockIdx.x * 4;

    for (int u = 0; u < 4; ++u) {
        const float4* src = (const float4*)(hin + (size_t)(node0 + u) * CT);
        float4* dst = (float4*)hL[u];
        for (int i = tid; i < CT/4; i += 256) dst[i] = src[i];
    }
    __syncthreads();
    for (int e = tid; e < 4*CT; e += 256) {
        int u = e / CT, i = e % CT;
        int c = i / TT, t = i % TT;       // i = c*12 + t
        Bs[u][t*KST + c] = f2bf(hL[u][i]);
    }
    __syncthreads();

    short8 Afr[4][2];
    #pragma unroll
    for (int mt = 0; mt < 4; ++mt)
        #pragma unroll
        for (int kc = 0; kc < 2; ++kc)
            Afr[mt][kc] = *(const short8*)(WtB + wid*4096 +
                                           (mt*16 + r)*64 + kc*32 + quad*8);

    int rcl = r < TT ? r : TT-1;

    for (int u = 0; u < 4; ++u) {
        floatx4 C[4];
        #pragma unroll
        for (int mt = 0; mt < 4; ++mt) C[mt] = (floatx4){0.f,0.f,0.f,0.f};
        #pragma unroll
        for (int kc = 0; kc < 2; ++kc) {
            short8 bfr = *(const short8*)&Bs[u][rcl*KST + kc*32 + quad*8];
            #pragma unroll
            for (int mt = 0; mt < 4; ++mt)
                C[mt] = __builtin_amdgcn_mfma_f32_16x16x32_bf16(Afr[mt][kc], bfr, C[mt], 0, 0, 0);
        }
        if (r < TT) {
            int node = node0 + u;
            int bb = node / NN, nn = node % NN;
            size_t row = ((size_t)((bb*HH + wid)*TT + r)*NN + nn)*FF;
            #pragma unroll
            for (int mt = 0; mt < 4; ++mt) {
                int f0 = mt*16 + quad*4;
                *(uint_t*)&Wh[row + f0]     = pkbf(C[mt][0], C[mt][1]);
                *(uint_t*)&Wh[row + f0 + 2] = pkbf(C[mt][2], C[mt][3]);
            }
        }
    }

    int t2 = lane & 15;
    if (t2 < TT) {
        int h2 = lane >> 4;
        const float* hLw = hL[wid];
        float s1 = 0.f, s2 = 0.f;
        for (int c = 0; c < CC; ++c) {
            float v = hLw[c*TT + t2];
            s1 += v * p1[h2*CC + c];
            s2 += v * p2[h2*CC + c];
        }
        int node = node0 + wid;
        int bb = node / NN, nn = node % NN;
        int idx = ((bb*HH + h2)*TT + t2)*NN + nn;
        e1[idx] = s1;
        e2[idx] = s2;
    }
}

// ---------------------------------------------------------------------------
// K2T: Wh[bht][n<500][64] -> WhT[bht][f=64][m=512] bf16, m>=500 zeroed.
// ---------------------------------------------------------------------------
__global__ __launch_bounds__(256) void k2t(const ushort_t* __restrict__ Wh,
                                           ushort_t* __restrict__ WhT) {
    __shared__ ushort_t tile[32*512];     // 32 KB
    int wid  = threadIdx.x >> 6;
    int lane = threadIdx.x & 63;
    int bht  = blockIdx.x >> 1;
    int fh   = blockIdx.x & 1;            // f half: f0 = fh*32
    const ushort_t* src = Wh + (size_t)bht * NN * FF + fh*32;

    for (int task = wid; task < 32; task += 4) {
        int i  = task >> 2;               // m-block of 64 (0..7)
        int fo = task & 3;                // f-octet within half (0..3)
        int m  = i*64 + lane;
        short8 v = {0,0,0,0,0,0,0,0};
        if (m < NN) v = *(const short8*)(src + m*FF + fo*8);
        #pragma unroll
        for (int j = 0; j < 8; ++j)
            tile[(fo*8 + j)*512 + m] = (ushort_t)v[j];
    }
    __syncthreads();

    ushort_t* dst = WhT + (size_t)bht * 64 * 512 + (size_t)fh*32*512;
    for (int f = wid; f < 32; f += 4) {
        short8 v = *(const short8*)&tile[f*512 + lane*8];
        *(short8*)(dst + f*512 + lane*8) = v;
    }
}

// ---------------------------------------------------------------------------
// K3: attention PV via MFMA — EXACT R12/R14 form.  ~50 us measured, stable.
// Five attempted improvements (R8/R9/R10/R13/R15) all regressed: this hot
// loop sits at the register-pressure knee.  FROZEN.
// ---------------------------------------------------------------------------
__global__ __launch_bounds__(256, 3) void k3_attn(const ushort_t* __restrict__ WhT,
                                                  const float* __restrict__ e1,
                                                  const float* __restrict__ e2,
                                                  const uint_t* __restrict__ maskbits,
                                                  ushort_t* __restrict__ hprB) {
    __shared__ float  e2s[512];           // 2 KB
    __shared__ uint_t mks[256*17];        // 17408 B
    int tid  = threadIdx.x;
    int wid  = tid >> 6;
    int lane = tid & 63;
    int bht  = blockIdx.x >> 1;
    int half = blockIdx.x & 1;
    int b    = bht / NBT;
    int ht   = bht % NBT;

    const float* e1p = e1 + (size_t)bht * NN;
    const float* e2p = e2 + (size_t)bht * NN;
    const ushort_t* WT = WhT + (size_t)bht * 64 * 512;
    const float L2E = 1.4426950408889634f;

    {
        int i = tid;
        e2s[i] = (i < NN) ? e2p[i] * L2E : 0.f;
        i = tid + 256;
        e2s[i] = (i < NN) ? e2p[i] * L2E : 0.f;
    }
    for (int i = tid; i < 256*16; i += 256) {
        int rl = i >> 4, dw = i & 15;
        mks[rl*17 + dw] = maskbits[(half*256 + rl)*16 + dw];
    }
    __syncthreads();

    int quad = lane >> 4;                 // 0..3
    int r    = lane & 15;                 // A-row / C-col

    const short8 ONES = {0x3F80,0x3F80,0x3F80,0x3F80,
                         0x3F80,0x3F80,0x3F80,0x3F80}; // bf16 1.0 x8

    float e1v[4];
    #pragma unroll
    for (int u = 0; u < 4; ++u) {
        int nrow = half*256 + (wid*4 + u)*16 + r;
        e1v[u] = ((nrow < NN) ? e1p[nrow] : 0.f) * L2E;
    }
    int rl0 = wid*64 + r;

    const ushort_t* WTr = WT + (size_t)r * 512;

    floatx4 C[4][4];
    floatx4 Cs[4];
    #pragma unroll
    for (int u = 0; u < 4; ++u) {
        Cs[u] = (floatx4){0.f,0.f,0.f,0.f};
        #pragma unroll
        for (int ft = 0; ft < 4; ++ft) C[u][ft] = (floatx4){0.f,0.f,0.f,0.f};
    }

    #pragma unroll
    for (int ki = 0; ki < 16; ++ki) {
        int kb = ki*32 + quad*8;

        short8 b0 = *(const short8*)(WTr + 0*8192 + kb);
        short8 b1 = *(const short8*)(WTr + 1*8192 + kb);
        short8 b2 = *(const short8*)(WTr + 2*8192 + kb);
        short8 b3 = *(const short8*)(WTr + 3*8192 + kb);

        float4 ea = *(const float4*)&e2s[kb];
        float4 eb = *(const float4*)&e2s[kb + 4];
        float ev[8] = {ea.x,ea.y,ea.z,ea.w, eb.x,eb.y,eb.z,eb.w};

        #pragma unroll
        for (int u = 0; u < 4; ++u) {
            uint_t md    = mks[(rl0 + u*16)*17 + ki];
            uint_t mbits = md >> (quad*8);
            union { uint_t w[4]; short8 s; } av;
            #pragma unroll
            for (int p = 0; p < 4; ++p) {
                float s0 = e1v[u] + ev[2*p];
                float s1 = e1v[u] + ev[2*p+1];
                float g0 = fmaxf(s0, 0.2f*s0);
                float g1 = fmaxf(s1, 0.2f*s1);
                float x0 = __builtin_amdgcn_exp2f(g0);
                float x1 = __builtin_amdgcn_exp2f(g1);
                x0 = (mbits & (1u << (2*p)))     ? x0 : 0.f;
                x1 = (mbits & (1u << (2*p + 1))) ? x1 : 0.f;
                av.w[p] = pkbf(x0, x1);
            }
            C[u][0] = __builtin_amdgcn_mfma_f32_16x16x32_bf16(av.s, b0, C[u][0], 0, 0, 0);
            C[u][1] = __builtin_amdgcn_mfma_f32_16x16x32_bf16(av.s, b1, C[u][1], 0, 0, 0);
            C[u][2] = __builtin_amdgcn_mfma_f32_16x16x32_bf16(av.s, b2, C[u][2], 0, 0, 0);
            C[u][3] = __builtin_amdgcn_mfma_f32_16x16x32_bf16(av.s, b3, C[u][3], 0, 0, 0);
            Cs[u]   = __builtin_amdgcn_mfma_f32_16x16x32_bf16(av.s, ONES, Cs[u], 0, 0, 0);
        }
    }

    #pragma unroll
    for (int u = 0; u < 4; ++u) {
        int n0 = half*256 + (wid*4 + u)*16;
        #pragma unroll
        for (int reg = 0; reg < 4; ++reg) {
            int n = n0 + quad*4 + reg;
            if (n < NN) {
                float inv = 1.0f / Cs[u][reg];
                size_t base = ((size_t)(b*NN + n)*NBT + ht)*FF;
                #pragma unroll
                for (int ft = 0; ft < 4; ++ft) {
                    float v = C[u][ft][reg] * inv;
                    v = v > 0.f ? v : __expf(v) - 1.f;
                    hprB[base + ft*16 + r] = f2bf(v);
                }
            }
        }
    }
}

// ---------------------------------------------------------------------------
// K4: head-mix 1x1 conv + residual via MFMA.  1 node per WAVE, 1000 blocks.
// NEW epilogue: stage per-wave outputs to LDS [o][t] (conflict-free), then
// coalesced float4 readback with the x-residual blended in (1 KB/instr h1
// writes, coalesced x reads).  Bit-identical arithmetic to R14.
// ---------------------------------------------------------------------------
__global__ __launch_bounds__(256) void k4_mfma(const ushort_t* __restrict__ hprB,
                                               const ushort_t* __restrict__ WgB,
                                               const float* __restrict__ bg,
                                               const float* __restrict__ xT,
                                               float* __restrict__ hnext) {
    __shared__ float S[4][CT];            // 12288 B
    int wid  = threadIdx.x >> 6;
    int lane = threadIdx.x & 63;
    int quad = lane >> 4;
    int r    = lane & 15;

    short8 Afr[4][8];
    #pragma unroll
    for (int ot = 0; ot < 4; ++ot)
        #pragma unroll
        for (int kc = 0; kc < 8; ++kc)
            Afr[ot][kc] = *(const short8*)(WgB + (size_t)(ot*16 + r)*HF + kc*32 + quad*8);

    float4 bgv[4];
    #pragma unroll
    for (int ot = 0; ot < 4; ++ot)
        bgv[ot] = *(const float4*)(bg + ot*16 + quad*4);

    int tcl = r < TT ? r : TT-1;

    int node = blockIdx.x*4 + wid;
    const ushort_t* P = hprB + (size_t)node * (NBT*FF);

    floatx4 C[4];
    #pragma unroll
    for (int ot = 0; ot < 4; ++ot) C[ot] = (floatx4){0.f,0.f,0.f,0.f};

    #pragma unroll
    for (int kc = 0; kc < 8; ++kc) {
        int k = kc*32 + quad*8;
        int h = k >> 6, f0 = k & 63;
        short8 bfr = *(const short8*)(P + (h*TT + tcl)*FF + f0);
        #pragma unroll
        for (int ot = 0; ot < 4; ++ot)
            C[ot] = __builtin_amdgcn_mfma_f32_16x16x32_bf16(Afr[ot][kc], bfr, C[ot], 0, 0, 0);
    }

    // stage v = C + bg to wave-private LDS [o][t]
    if (r < TT) {
        #pragma unroll
        for (int ot = 0; ot < 4; ++ot) {
            #pragma unroll
            for (int reg = 0; reg < 4; ++reg) {
                int o = ot*16 + quad*4 + reg;
                S[wid][o*TT + r] = C[ot][reg] + bgv[ot][reg];
            }
        }
    }
    // wave-local readback (no barrier): blend residual, coalesced writes
    {
        const float4* xp4 = (const float4*)(xT + (size_t)node * CT);
        float4* ho4 = (float4*)(hnext + (size_t)node * CT);
        const float4* S4 = (const float4*)S[wid];
        #pragma unroll
        for (int j = 0; j < 3; ++j) {
            int i = lane + j*64;
            float4 xv = xp4[i];
            float4 sv = S4[i];
            float4 ov;
            ov.x = 0.05f*xv.x + 0.95f*sv.x;
            ov.y = 0.05f*xv.y + 0.95f*sv.y;
            ov.z = 0.05f*xv.z + 0.95f*sv.z;
            ov.w = 0.05f*xv.w + 0.95f*sv.w;
            ho4[i] = ov;
        }
    }
}

// ---------------------------------------------------------------------------
// K45: fused layer-2 head-mix + final mix, BOTH via MFMA.  1 node/wave.
// NEW epilogue: stage out values to LDS [wid][o][t], barrier, cooperative
// write of 192 B-contiguous (4-node x 12-t) chunks per o.
// ---------------------------------------------------------------------------
__global__ __launch_bounds__(256) void k45_fused(const ushort_t* __restrict__ hprB,
                                                 const ushort_t* __restrict__ WgB,
                                                 const float* __restrict__ bg,
                                                 const float* __restrict__ xT,
                                                 const float* __restrict__ h1,
                                                 const ushort_t* __restrict__ WmB,
                                                 const float* __restrict__ bm,
                                                 float* __restrict__ out) {
    __shared__ ushort_t Bs[4][TT*BSR];    // 19200 B
    __shared__ float    So[4][CT];        // 12288 B  (total 31488 B)
    int wid  = threadIdx.x >> 6;
    int lane = threadIdx.x & 63;
    int quad = lane >> 4;
    int r    = lane & 15;

    int node = blockIdx.x*4 + wid;
    ushort_t* Bw = Bs[wid];

    {   // stage x, h1 -> bf16 [t][c] (lane = channel c)
        const float* xp = xT + (size_t)node*CT + lane*TT;
        const float* hp = h1 + (size_t)node*CT + lane*TT;
        float4 x0 = *(const float4*)(xp);
        float4 x1 = *(const float4*)(xp + 4);
        float4 x2 = *(const float4*)(xp + 8);
        float4 g0 = *(const float4*)(hp);
        float4 g1 = *(const float4*)(hp + 4);
        float4 g2 = *(const float4*)(hp + 8);
        float xa[12] = {x0.x,x0.y,x0.z,x0.w, x1.x,x1.y,x1.z,x1.w,
                        x2.x,x2.y,x2.z,x2.w};
        float ha[12] = {g0.x,g0.y,g0.z,g0.w, g1.x,g1.y,g1.z,g1.w,
                        g2.x,g2.y,g2.z,g2.w};
        #pragma unroll
        for (int t = 0; t < TT; ++t) {
            Bw[t*BSR + lane]      = f2bf(xa[t]);
            Bw[t*BSR + 64 + lane] = f2bf(ha[t]);
        }
    }

    // ---- phase 1 (k4 body): h2 via MFMA -> Bs section 2 ----
    {
        short8 Afr[4][8];
        #pragma unroll
        for (int ot = 0; ot < 4; ++ot)
            #pragma unroll
            for (int kc = 0; kc < 8; ++kc)
                Afr[ot][kc] = *(const short8*)(WgB + (size_t)(ot*16 + r)*HF + kc*32 + quad*8);
        float4 bgv[4];
        #pragma unroll
        for (int ot = 0; ot < 4; ++ot)
            bgv[ot] = *(const float4*)(bg + ot*16 + quad*4);

        int tcl = r < TT ? r : TT-1;
        const ushort_t* P = hprB + (size_t)node * (NBT*FF);

        floatx4 C[4];
        #pragma unroll
        for (int ot = 0; ot < 4; ++ot) C[ot] = (floatx4){0.f,0.f,0.f,0.f};
        #pragma unroll
        for (int kc = 0; kc < 8; ++kc) {
            int k = kc*32 + quad*8;
            int h = k >> 6, f0 = k & 63;
            short8 bfr = *(const short8*)(P + (h*TT + tcl)*FF + f0);
            #pragma unroll
            for (int ot = 0; ot < 4; ++ot)
                C[ot] = __builtin_amdgcn_mfma_f32_16x16x32_bf16(Afr[ot][kc], bfr, C[ot], 0, 0, 0);
        }

        if (r < TT) {
            const float* xp = xT + (size_t)node * CT;
            #pragma unroll
            for (int ot = 0; ot < 4; ++ot) {
                #pragma unroll
                for (int rp = 0; rp < 4; rp += 2) {
                    int o = ot*16 + quad*4 + rp;
                    float v0 = C[ot][rp]   + bgv[ot][rp];
                    float v1 = C[ot][rp+1] + bgv[ot][rp+1];
                    float h20 = 0.05f*xp[o*TT + r]       + 0.95f*v0;
                    float h21 = 0.05f*xp[(o+1)*TT + r]   + 0.95f*v1;
                    *(uint_t*)&Bw[r*BSR + 128 + o] = pkbf(h20, h21);
                }
            }
        }
    }

    // ---- phase 2 (k5 body): out = bm + WmB @ [x|h1|h2] via MFMA ----
    {
        short8 Am[4][6];
        #pragma unroll
        for (int ot = 0; ot < 4; ++ot)
            #pragma unroll
            for (int kc = 0; kc < 6; ++kc)
                Am[ot][kc] = *(const short8*)(WmB + (size_t)(ot*16 + r)*(3*CC) + kc*32 + quad*8);

        int trd = r < TT ? r : TT-1;      // clamp (rows 12..15 unused)
        floatx4 C2[4];
        #pragma unroll
        for (int ot = 0; ot < 4; ++ot) C2[ot] = (floatx4){0.f,0.f,0.f,0.f};
        #pragma unroll
        for (int kc = 0; kc < 6; ++kc) {
            short8 bfr = *(const short8*)&Bw[trd*BSR + kc*32 + quad*8];
            #pragma unroll
            for (int ot = 0; ot < 4; ++ot)
                C2[ot] = __builtin_amdgcn_mfma_f32_16x16x32_bf16(Am[ot][kc], bfr, C2[ot], 0, 0, 0);
        }

        // stage out values to LDS [wid][o][t]
        if (r < TT) {
            #pragma unroll
            for (int ot = 0; ot < 4; ++ot) {
                float4 bmv = *(const float4*)(bm + ot*16 + quad*4);
                #pragma unroll
                for (int reg = 0; reg < 4; ++reg) {
                    int o = ot*16 + quad*4 + reg;
                    So[wid][o*TT + r] = C2[ot][reg] + bmv[reg];
                }
            }
        }
    }
    __syncthreads();

    // cooperative coalesced out-write: thread (o = tid>>2, q = tid&3)
    // writes node (block*4+q)'s 12 floats for channel o (48 B, part of a
    // 192 B contiguous 4-node chunk).
    {
        int o = threadIdx.x >> 2;
        int q = threadIdx.x & 3;
        int nodeq = blockIdx.x*4 + q;
        int bq = nodeq / NN, nq = nodeq % NN;
        float* op = out + ((size_t)(bq*CC + o)*NN + nq)*TT;
        const float* Sp = So[q] + o*TT;
        *(float4*)&op[0] = *(const float4*)&Sp[0];
        *(float4*)&op[4] = *(const float4*)&Sp[4];
        *(float4*)&op[8] = *(const float4*)&Sp[8];
    }
}

// ---------------------------------------------------------------------------
extern "C" void kernel_launch(void* const* d_in, const int* in_sizes, int n_in,
                              void* d_out, int out_size, void* d_ws, size_t ws_size,
                              hipStream_t stream) {
    const float* x   = (const float*)d_in[0];
    const float* adj = (const float*)d_in[1];
    const float* W   = (const float*)d_in[2];
    const float* a1  = (const float*)d_in[3];
    const float* a2  = (const float*)d_in[4];
    const float* Wg  = (const float*)d_in[5];
    const float* bg  = (const float*)d_in[6];
    const float* Wm  = (const float*)d_in[7];
    const float* bm  = (const float*)d_in[8];
    float* out = (float*)d_out;

    char* ws = (char*)d_ws;
    size_t off = 0;
    auto alloc = [&](size_t bytes) -> void* {
        void* p = ws + off;
        off += (bytes + 255) & ~(size_t)255;
        return p;
    };

    uint_t* maskbits = (uint_t*)alloc((size_t)512 * 16 * 4);                // 32 KB
    float* p1   = (float*)alloc(HH*CC * sizeof(float));
    float* p2   = (float*)alloc(HH*CC * sizeof(float));
    ushort_t* WmB = (ushort_t*)alloc((size_t)CC*3*CC * 2);                  // 24.6 KB
    ushort_t* WgB = (ushort_t*)alloc((size_t)FF*HF * 2);
    ushort_t* WtB = (ushort_t*)alloc((size_t)HH*CC*FF * 2);                 // 32 KB
    float* xT   = (float*)alloc((size_t)NNODE * CT * sizeof(float));        // 12.3 MB
    ushort_t* Wh   = (ushort_t*)alloc((size_t)NROWS * FF * 2);              // 24.6 MB
    ushort_t* WhT  = (ushort_t*)alloc((size_t)NBHT * 64 * 512 * 2);         // 25.2 MB
    ushort_t* hprB = (ushort_t*)alloc((size_t)NNODE * NBT * FF * 2);        // 24.6 MB
    float* e1   = (float*)alloc((size_t)NROWS * sizeof(float));
    float* e2   = (float*)alloc((size_t)NROWS * sizeof(float));
    float* h1   = (float*)alloc((size_t)NNODE * CT * sizeof(float));        // 12.3 MB
    (void)ws_size;

    k016_setup<<<465, 256, 0, stream>>>(adj, W, a1, a2, Wm, Wg, x,
                                        maskbits, p1, p2, WmB, WgB, WtB, xT);

    // layer 1
    k2_wh_e <<<NNODE/4, 256, 0, stream>>>(xT, WtB, p1, p2, Wh, e1, e2);
    k2t     <<<NBHT*2,  256, 0, stream>>>(Wh, WhT);
    k3_attn <<<NBHT*2,  256, 0, stream>>>(WhT, e1, e2, maskbits, hprB);
    k4_mfma <<<NNODE/4, 256, 0, stream>>>(hprB, WgB, bg, xT, h1);

    // layer 2
    k2_wh_e <<<NNODE/4, 256, 0, stream>>>(h1, WtB, p1, p2, Wh, e1, e2);
    k2t     <<<NBHT*2,  256, 0, stream>>>(Wh, WhT);
    k3_attn <<<NBHT*2,  256, 0, stream>>>(WhT, e1, e2, maskbits, hprB);

    // fused layer-2 mix + final (both matmuls on MFMA)
    k45_fused<<<NNODE/4, 256, 0, stream>>>(hprB, WgB, bg, xT, h1, WmB, bm, out);
}

// Round 18
// 303.244 us; speedup vs baseline: 1.0053x; 1.0053x over previous
//
#include <hip/hip_runtime.h>
#include <hip/hip_bf16.h>
#include <math.h>

#define BB 8
#define CC 64
#define NN 500
#define TT 12
#define HH 4
#define FF 64
#define CT (CC*TT)      // 768
#define HF (HH*FF)      // 256
#define NBT (HH*TT)     // 48
#define NBHT (BB*NBT)   // 384
#define NROWS (BB*HH*TT*NN)  // 192000
#define NNODE (BB*NN)   // 4000
#define BSR 200         // k45 LDS row stride (ushorts)
#define KST 68          // k2 LDS B row stride (ushorts)
#define WTS 520         // k2 WT-lds t-row stride (ushorts): 1040B, 16B-aligned

typedef unsigned short ushort_t;
typedef unsigned int uint_t;
typedef __attribute__((ext_vector_type(8))) short short8;
typedef __attribute__((ext_vector_type(4))) float floatx4;

static __device__ __forceinline__ ushort_t f2bf(float v) {
    __hip_bfloat16 h = __float2bfloat16(v);
    ushort_t u;
    __builtin_memcpy(&u, &h, 2);
    return u;
}

// pack two f32 -> packed bf16 (lo = a, hi = b), RNE (hw v_cvt_pk on gfx950)
static __device__ __forceinline__ uint_t pkbf(float a, float b) {
    __hip_bfloat162 h = __float22bfloat162_rn(make_float2(a, b));
    uint_t u;
    __builtin_memcpy(&u, &h, 4);
    return u;
}

// ---------------------------------------------------------------------------
// K016: merged setup + x-transpose + WhT tail zero.
// Blocks [0,32):    bitmask[512][16 dwords] of (adj+I)>0.
// Blocks [32,209):  p1/p2 folds, WmB=bf16(Wm), WgB=bf16(Wg), WtB=bf16(W^T).
// Blocks [209,465): transpose x -> xT node-major.
// Blocks [465,561): zero WhT m-tail [500,512) for all (bht,f) rows.
// ---------------------------------------------------------------------------
__global__ __launch_bounds__(256) void k016_setup(const float* __restrict__ adj,
                                                  const float* __restrict__ W,
                                                  const float* __restrict__ a1,
                                                  const float* __restrict__ a2,
                                                  const float* __restrict__ Wm,
                                                  const float* __restrict__ Wg,
                                                  const float* __restrict__ x,
                                                  uint_t* __restrict__ maskbits,
                                                  float* __restrict__ p1,
                                                  float* __restrict__ p2,
                                                  ushort_t* __restrict__ WmB,
                                                  ushort_t* __restrict__ WgB,
                                                  ushort_t* __restrict__ WtB,
                                                  float* __restrict__ xT,
                                                  ushort_t* __restrict__ WhT) {
    __shared__ float tile[16*776];   // used by the x-transpose path only
    int blk = blockIdx.x;
    if (blk < 32) {
        int idx = blk * 256 + threadIdx.x;   // < 512*16
        int n = idx >> 4, j = idx & 15;      // dword j covers m = j*32..+31
        uint_t v = 0;
        if (n < NN) {
            int m0 = j * 32;
            for (int i = 0; i < 32; ++i) {
                int m = m0 + i;
                bool p = (m < NN) && (adj[n*NN + m] > 0.f || m == n);
                v |= (p ? 1u : 0u) << i;
            }
        }
        maskbits[idx] = v;
        return;
    }
    if (blk < 209) {
        int idx = (blk - 32) * 256 + threadIdx.x;
        if (idx < HH*CC) {
            int h = idx / CC, c = idx % CC;
            float s1 = 0.f, s2 = 0.f;
            for (int f = 0; f < FF; ++f) {
                float w = W[(h*CC + c)*FF + f];
                s1 += w * a1[h*FF + f];
                s2 += w * a2[h*FF + f];
            }
            p1[idx] = s1; p2[idx] = s2;
        }
        int j = idx - HH*CC;
        if (j >= 0 && j < CC*3*CC) {          // WmB = bf16(Wm), [o][192]
            WmB[j] = f2bf(Wm[j]);
        }
        int j2 = idx - (HH*CC + CC*3*CC);
        if (j2 >= 0 && j2 < FF*HF) {
            WgB[j2] = f2bf(Wg[j2]);
        }
        int j3 = idx - (HH*CC + CC*3*CC + FF*HF);
        if (j3 >= 0 && j3 < HH*CC*FF) {       // WtB[h][f][c] = W[h][c][f]
            int h = j3 >> 12, rem = j3 & 4095;
            int f = rem >> 6, c = rem & 63;
            WtB[j3] = f2bf(W[h*4096 + c*64 + f]);
        }
        return;
    }
    if (blk >= 465) {                         // WhT tail zero: m in [500,512)
        int row = (blk - 465) * 256 + threadIdx.x;   // < 24576 = 384*64
        uint_t* p = (uint_t*)(WhT + (size_t)row * 512 + 500);
        #pragma unroll
        for (int j = 0; j < 6; ++j) p[j] = 0;
        return;
    }
    // x-transpose: blocks 209..464 -> xblk 0..255
    int xblk = blk - 209;
    int b  = xblk >> 5;
    int n0 = (xblk & 31) * 16;
    for (int idx = threadIdx.x; idx < CC*16*TT; idx += 256) {
        int c   = idx / (16*TT);
        int rem = idx % (16*TT);
        int nl  = rem / TT;
        int t   = rem % TT;
        int n   = n0 + nl;
        if (n < NN)
            tile[nl*776 + c*TT + t] = x[((b*CC + c)*NN + n)*TT + t];
    }
    __syncthreads();
    for (int idx = threadIdx.x; idx < 16*CT; idx += 256) {
        int nl = idx / CT;
        int j  = idx % CT;
        int n  = n0 + nl;
        if (n < NN)
            xT[(size_t)(b*NN + n)*CT + j] = tile[nl*776 + j];
    }
}

// ---------------------------------------------------------------------------
// K2: Wh via MFMA, writing WhT DIRECTLY (k2t eliminated).
// Block = 8 nodes (grid 8b x 63, tail-masked); wave = head h.
// Phase A: stage fp32 hL (union region), build bf16 Bs rows, e1/e2 (fp32,
//          byte-identical path).  Phase B (hL dead -> union reused): per-u
//          MFMA, results scattered to per-wave WT-lds [t][f][8m] (bf16,
//          <=4-way write banks), then 16B/lane global stores: one short8
//          per (t,f) row covering 8 consecutive m.  WhT bits identical to
//          the old Wh->k2t path (same RNE conversions).
// ---------------------------------------------------------------------------
__global__ __launch_bounds__(256) void k2_wh_e(const float* __restrict__ hin,
                                               const ushort_t* __restrict__ WtB,
                                               const float* __restrict__ p1,
                                               const float* __restrict__ p2,
                                               ushort_t* __restrict__ WhT,
                                               float* __restrict__ e1,
                                               float* __restrict__ e2) {
    __shared__ char uni[4*TT*WTS*2];      // 49920 B: fp32 hL[8][768] then WT[4][12][520]
    __shared__ ushort_t Bs[8][TT*KST];    // 13056 B
    float (*hL)[CT] = (float(*)[CT])uni;
    int tid  = threadIdx.x;
    int wid  = tid >> 6;                  // wave = head h
    int lane = tid & 63;
    int quad = lane >> 4;
    int r    = lane & 15;
    int b    = blockIdx.x / 63;
    int nl0  = (blockIdx.x % 63) * 8;     // local m base (0..496)

    // stage fp32 (coalesced float4; clamp OOB tail reads)
    for (int i = tid; i < 8*(CT/4); i += 256) {
        int u = i / (CT/4), j = i % (CT/4);
        int node = b*NN + nl0 + u;
        if (node > NNODE-1) node = NNODE-1;
        ((float4*)hL[u])[j] = ((const float4*)(hin + (size_t)node*CT))[j];
    }
    __syncthreads();
    // bf16 [t][c] rows
    for (int e = tid; e < 8*CT; e += 256) {
        int u = e / CT, i = e % CT;
        int c = i / TT, t = i % TT;       // i = c*12 + t
        Bs[u][t*KST + c] = f2bf(hL[u][i]);
    }
    // e1/e2 (fp32, unchanged numerics); wave covers local nodes wid, wid+4
    {
        int t2 = lane & 15, h2 = lane >> 4;
        if (t2 < TT) {
            for (int pass = 0; pass < 2; ++pass) {
                int u  = wid + pass*4;
                int nl = nl0 + u;
                if (nl < NN) {
                    const float* hLw = hL[u];
                    float s1 = 0.f, s2 = 0.f;
                    for (int c = 0; c < CC; ++c) {
                        float v = hLw[c*TT + t2];
                        s1 += v * p1[h2*CC + c];
                        s2 += v * p2[h2*CC + c];
                    }
                    int idx = ((b*HH + h2)*TT + t2)*NN + nl;
                    e1[idx] = s1;
                    e2[idx] = s2;
                }
            }
        }
    }
    __syncthreads();                      // hL dead; union becomes WT-lds

    ushort_t* WTl = (ushort_t*)uni + wid*(TT*WTS);   // [12][520]

    short8 Afr[4][2];
    #pragma unroll
    for (int mt = 0; mt < 4; ++mt)
        #pragma unroll
        for (int kc = 0; kc < 2; ++kc)
            Afr[mt][kc] = *(const short8*)(WtB + wid*4096 +
                                           (mt*16 + r)*64 + kc*32 + quad*8);

    int rcl = r < TT ? r : TT-1;

    for (int u = 0; u < 8; ++u) {
        bool valid = (nl0 + u) < NN;
        floatx4 C[4];
        #pragma unroll
        for (int mt = 0; mt < 4; ++mt) C[mt] = (floatx4){0.f,0.f,0.f,0.f};
        #pragma unroll
        for (int kc = 0; kc < 2; ++kc) {
            short8 bfr = *(const short8*)&Bs[u][rcl*KST + kc*32 + quad*8];
            #pragma unroll
            for (int mt = 0; mt < 4; ++mt)
                C[mt] = __builtin_amdgcn_mfma_f32_16x16x32_bf16(Afr[mt][kc], bfr, C[mt], 0, 0, 0);
        }
        if (r < TT) {
            #pragma unroll
            for (int mt = 0; mt < 4; ++mt) {
                #pragma unroll
                for (int reg = 0; reg < 4; ++reg) {
                    int f = mt*16 + quad*4 + reg;
                    WTl[r*WTS + f*8 + u] = valid ? f2bf(C[mt][reg]) : (ushort_t)0;
                }
            }
        }
    }

    // global write: 12 t-rows; lane = f; 16B short8 covers m = nl0..nl0+7
    {
        size_t base = ((size_t)(b*NBT + wid*TT) * 64) * 512 + nl0;
        #pragma unroll
        for (int t = 0; t < TT; ++t) {
            short8 v = *(const short8*)&WTl[t*WTS + lane*8];
            *(short8*)(WhT + base + ((size_t)t*64 + lane)*512) = v;
        }
    }
}

// ---------------------------------------------------------------------------
// K3: attention PV via MFMA — EXACT R12/R14 form.  ~50 us measured, stable.
// Five attempted improvements (R8/R9/R10/R13/R15) all regressed.  FROZEN.
// ---------------------------------------------------------------------------
__global__ __launch_bounds__(256, 3) void k3_attn(const ushort_t* __restrict__ WhT,
                                                  const float* __restrict__ e1,
                                                  const float* __restrict__ e2,
                                                  const uint_t* __restrict__ maskbits,
                                                  ushort_t* __restrict__ hprB) {
    __shared__ float  e2s[512];           // 2 KB
    __shared__ uint_t mks[256*17];        // 17408 B
    int tid  = threadIdx.x;
    int wid  = tid >> 6;
    int lane = tid & 63;
    int bht  = blockIdx.x >> 1;
    int half = blockIdx.x & 1;
    int b    = bht / NBT;
    int ht   = bht % NBT;

    const float* e1p = e1 + (size_t)bht * NN;
    const float* e2p = e2 + (size_t)bht * NN;
    const ushort_t* WT = WhT + (size_t)bht * 64 * 512;
    const float L2E = 1.4426950408889634f;

    {
        int i = tid;
        e2s[i] = (i < NN) ? e2p[i] * L2E : 0.f;
        i = tid + 256;
        e2s[i] = (i < NN) ? e2p[i] * L2E : 0.f;
    }
    for (int i = tid; i < 256*16; i += 256) {
        int rl = i >> 4, dw = i & 15;
        mks[rl*17 + dw] = maskbits[(half*256 + rl)*16 + dw];
    }
    __syncthreads();

    int quad = lane >> 4;                 // 0..3
    int r    = lane & 15;                 // A-row / C-col

    const short8 ONES = {0x3F80,0x3F80,0x3F80,0x3F80,
                         0x3F80,0x3F80,0x3F80,0x3F80}; // bf16 1.0 x8

    float e1v[4];
    #pragma unroll
    for (int u = 0; u < 4; ++u) {
        int nrow = half*256 + (wid*4 + u)*16 + r;
        e1v[u] = ((nrow < NN) ? e1p[nrow] : 0.f) * L2E;
    }
    int rl0 = wid*64 + r;

    const ushort_t* WTr = WT + (size_t)r * 512;

    floatx4 C[4][4];
    floatx4 Cs[4];
    #pragma unroll
    for (int u = 0; u < 4; ++u) {
        Cs[u] = (floatx4){0.f,0.f,0.f,0.f};
        #pragma unroll
        for (int ft = 0; ft < 4; ++ft) C[u][ft] = (floatx4){0.f,0.f,0.f,0.f};
    }

    #pragma unroll
    for (int ki = 0; ki < 16; ++ki) {
        int kb = ki*32 + quad*8;

        short8 b0 = *(const short8*)(WTr + 0*8192 + kb);
        short8 b1 = *(const short8*)(WTr + 1*8192 + kb);
        short8 b2 = *(const short8*)(WTr + 2*8192 + kb);
        short8 b3 = *(const short8*)(WTr + 3*8192 + kb);

        float4 ea = *(const float4*)&e2s[kb];
        float4 eb = *(const float4*)&e2s[kb + 4];
        float ev[8] = {ea.x,ea.y,ea.z,ea.w, eb.x,eb.y,eb.z,eb.w};

        #pragma unroll
        for (int u = 0; u < 4; ++u) {
            uint_t md    = mks[(rl0 + u*16)*17 + ki];
            uint_t mbits = md >> (quad*8);
            union { uint_t w[4]; short8 s; } av;
            #pragma unroll
            for (int p = 0; p < 4; ++p) {
                float s0 = e1v[u] + ev[2*p];
                float s1 = e1v[u] + ev[2*p+1];
                float g0 = fmaxf(s0, 0.2f*s0);
                float g1 = fmaxf(s1, 0.2f*s1);
                float x0 = __builtin_amdgcn_exp2f(g0);
                float x1 = __builtin_amdgcn_exp2f(g1);
                x0 = (mbits & (1u << (2*p)))     ? x0 : 0.f;
                x1 = (mbits & (1u << (2*p + 1))) ? x1 : 0.f;
                av.w[p] = pkbf(x0, x1);
            }
            C[u][0] = __builtin_amdgcn_mfma_f32_16x16x32_bf16(av.s, b0, C[u][0], 0, 0, 0);
            C[u][1] = __builtin_amdgcn_mfma_f32_16x16x32_bf16(av.s, b1, C[u][1], 0, 0, 0);
            C[u][2] = __builtin_amdgcn_mfma_f32_16x16x32_bf16(av.s, b2, C[u][2], 0, 0, 0);
            C[u][3] = __builtin_amdgcn_mfma_f32_16x16x32_bf16(av.s, b3, C[u][3], 0, 0, 0);
            Cs[u]   = __builtin_amdgcn_mfma_f32_16x16x32_bf16(av.s, ONES, Cs[u], 0, 0, 0);
        }
    }

    #pragma unroll
    for (int u = 0; u < 4; ++u) {
        int n0 = half*256 + (wid*4 + u)*16;
        #pragma unroll
        for (int reg = 0; reg < 4; ++reg) {
            int n = n0 + quad*4 + reg;
            if (n < NN) {
                float inv = 1.0f / Cs[u][reg];
                size_t base = ((size_t)(b*NN + n)*NBT + ht)*FF;
                #pragma unroll
                for (int ft = 0; ft < 4; ++ft) {
                    float v = C[u][ft][reg] * inv;
                    v = v > 0.f ? v : __expf(v) - 1.f;
                    hprB[base + ft*16 + r] = f2bf(v);
                }
            }
        }
    }
}

// ---------------------------------------------------------------------------
// K4: head-mix 1x1 conv + residual via MFMA.  1 node per WAVE, 1000 blocks.
// ---------------------------------------------------------------------------
__global__ __launch_bounds__(256) void k4_mfma(const ushort_t* __restrict__ hprB,
                                               const ushort_t* __restrict__ WgB,
                                               const float* __restrict__ bg,
                                               const float* __restrict__ xT,
                                               float* __restrict__ hnext) {
    __shared__ float S[4][CT];            // 12288 B
    int wid  = threadIdx.x >> 6;
    int lane = threadIdx.x & 63;
    int quad = lane >> 4;
    int r    = lane & 15;

    short8 Afr[4][8];
    #pragma unroll
    for (int ot = 0; ot < 4; ++ot)
        #pragma unroll
        for (int kc = 0; kc < 8; ++kc)
            Afr[ot][kc] = *(const short8*)(WgB + (size_t)(ot*16 + r)*HF + kc*32 + quad*8);

    float4 bgv[4];
    #pragma unroll
    for (int ot = 0; ot < 4; ++ot)
        bgv[ot] = *(const float4*)(bg + ot*16 + quad*4);

    int tcl = r < TT ? r : TT-1;

    int node = blockIdx.x*4 + wid;
    const ushort_t* P = hprB + (size_t)node * (NBT*FF);

    floatx4 C[4];
    #pragma unroll
    for (int ot = 0; ot < 4; ++ot) C[ot] = (floatx4){0.f,0.f,0.f,0.f};

    #pragma unroll
    for (int kc = 0; kc < 8; ++kc) {
        int k = kc*32 + quad*8;
        int h = k >> 6, f0 = k & 63;
        short8 bfr = *(const short8*)(P + (h*TT + tcl)*FF + f0);
        #pragma unroll
        for (int ot = 0; ot < 4; ++ot)
            C[ot] = __builtin_amdgcn_mfma_f32_16x16x32_bf16(Afr[ot][kc], bfr, C[ot], 0, 0, 0);
    }

    if (r < TT) {
        #pragma unroll
        for (int ot = 0; ot < 4; ++ot) {
            #pragma unroll
            for (int reg = 0; reg < 4; ++reg) {
                int o = ot*16 + quad*4 + reg;
                S[wid][o*TT + r] = C[ot][reg] + bgv[ot][reg];
            }
        }
    }
    {
        const float4* xp4 = (const float4*)(xT + (size_t)node * CT);
        float4* ho4 = (float4*)(hnext + (size_t)node * CT);
        const float4* S4 = (const float4*)S[wid];
        #pragma unroll
        for (int j = 0; j < 3; ++j) {
            int i = lane + j*64;
            float4 xv = xp4[i];
            float4 sv = S4[i];
            float4 ov;
            ov.x = 0.05f*xv.x + 0.95f*sv.x;
            ov.y = 0.05f*xv.y + 0.95f*sv.y;
            ov.z = 0.05f*xv.z + 0.95f*sv.z;
            ov.w = 0.05f*xv.w + 0.95f*sv.w;
            ho4[i] = ov;
        }
    }
}

// ---------------------------------------------------------------------------
// K45: fused layer-2 head-mix + final mix, BOTH via MFMA.  1 node/wave.
// ---------------------------------------------------------------------------
__global__ __launch_bounds__(256) void k45_fused(const ushort_t* __restrict__ hprB,
                                                 const ushort_t* __restrict__ WgB,
                                                 const float* __restrict__ bg,
                                                 const float* __restrict__ xT,
                                                 const float* __restrict__ h1,
                                                 const ushort_t* __restrict__ WmB,
                                                 const float* __restrict__ bm,
                                                 float* __restrict__ out) {
    __shared__ ushort_t Bs[4][TT*BSR];    // 19200 B
    __shared__ float    So[4][CT];        // 12288 B
    int wid  = threadIdx.x >> 6;
    int lane = threadIdx.x & 63;
    int quad = lane >> 4;
    int r    = lane & 15;

    int node = blockIdx.x*4 + wid;
    ushort_t* Bw = Bs[wid];

    {   // stage x, h1 -> bf16 [t][c] (lane = channel c)
        const float* xp = xT + (size_t)node*CT + lane*TT;
        const float* hp = h1 + (size_t)node*CT + lane*TT;
        float4 x0 = *(const float4*)(xp);
        float4 x1 = *(const float4*)(xp + 4);
        float4 x2 = *(const float4*)(xp + 8);
        float4 g0 = *(const float4*)(hp);
        float4 g1 = *(const float4*)(hp + 4);
        float4 g2 = *(const float4*)(hp + 8);
        float xa[12] = {x0.x,x0.y,x0.z,x0.w, x1.x,x1.y,x1.z,x1.w,
                        x2.x,x2.y,x2.z,x2.w};
        float ha[12] = {g0.x,g0.y,g0.z,g0.w, g1.x,g1.y,g1.z,g1.w,
                        g2.x,g2.y,g2.z,g2.w};
        #pragma unroll
        for (int t = 0; t < TT; ++t) {
            Bw[t*BSR + lane]      = f2bf(xa[t]);
            Bw[t*BSR + 64 + lane] = f2bf(ha[t]);
        }
    }

    // ---- phase 1 (k4 body): h2 via MFMA -> Bs section 2 ----
    {
        short8 Afr[4][8];
        #pragma unroll
        for (int ot = 0; ot < 4; ++ot)
            #pragma unroll
            for (int kc = 0; kc < 8; ++kc)
                Afr[ot][kc] = *(const short8*)(WgB + (size_t)(ot*16 + r)*HF + kc*32 + quad*8);
        float4 bgv[4];
        #pragma unroll
        for (int ot = 0; ot < 4; ++ot)
            bgv[ot] = *(const float4*)(bg + ot*16 + quad*4);

        int tcl = r < TT ? r : TT-1;
        const ushort_t* P = hprB + (size_t)node * (NBT*FF);

        floatx4 C[4];
        #pragma unroll
        for (int ot = 0; ot < 4; ++ot) C[ot] = (floatx4){0.f,0.f,0.f,0.f};
        #pragma unroll
        for (int kc = 0; kc < 8; ++kc) {
            int k = kc*32 + quad*8;
            int h = k >> 6, f0 = k & 63;
            short8 bfr = *(const short8*)(P + (h*TT + tcl)*FF + f0);
            #pragma unroll
            for (int ot = 0; ot < 4; ++ot)
                C[ot] = __builtin_amdgcn_mfma_f32_16x16x32_bf16(Afr[ot][kc], bfr, C[ot], 0, 0, 0);
        }

        if (r < TT) {
            const float* xp = xT + (size_t)node * CT;
            #pragma unroll
            for (int ot = 0; ot < 4; ++ot) {
                #pragma unroll
                for (int rp = 0; rp < 4; rp += 2) {
                    int o = ot*16 + quad*4 + rp;
                    float v0 = C[ot][rp]   + bgv[ot][rp];
                    float v1 = C[ot][rp+1] + bgv[ot][rp+1];
                    float h20 = 0.05f*xp[o*TT + r]       + 0.95f*v0;
                    float h21 = 0.05f*xp[(o+1)*TT + r]   + 0.95f*v1;
                    *(uint_t*)&Bw[r*BSR + 128 + o] = pkbf(h20, h21);
                }
            }
        }
    }

    // ---- phase 2 (k5 body): out = bm + WmB @ [x|h1|h2] via MFMA ----
    {
        short8 Am[4][6];
        #pragma unroll
        for (int ot = 0; ot < 4; ++ot)
            #pragma unroll
            for (int kc = 0; kc < 6; ++kc)
                Am[ot][kc] = *(const short8*)(WmB + (size_t)(ot*16 + r)*(3*CC) + kc*32 + quad*8);

        int trd = r < TT ? r : TT-1;      // clamp (rows 12..15 unused)
        floatx4 C2[4];
        #pragma unroll
        for (int ot = 0; ot < 4; ++ot) C2[ot] = (floatx4){0.f,0.f,0.f,0.f};
        #pragma unroll
        for (int kc = 0; kc < 6; ++kc) {
            short8 bfr = *(const short8*)&Bw[trd*BSR + kc*32 + quad*8];
            #pragma unroll
            for (int ot = 0; ot < 4; ++ot)
                C2[ot] = __builtin_amdgcn_mfma_f32_16x16x32_bf16(Am[ot][kc], bfr, C2[ot], 0, 0, 0);
        }

        if (r < TT) {
            #pragma unroll
            for (int ot = 0; ot < 4; ++ot) {
                float4 bmv = *(const float4*)(bm + ot*16 + quad*4);
                #pragma unroll
                for (int reg = 0; reg < 4; ++reg) {
                    int o = ot*16 + quad*4 + reg;
                    So[wid][o*TT + r] = C2[ot][reg] + bmv[reg];
                }
            }
        }
    }
    __syncthreads();

    {
        int o = threadIdx.x >> 2;
        int q = threadIdx.x & 3;
        int nodeq = blockIdx.x*4 + q;
        int bq = nodeq / NN, nq = nodeq % NN;
        float* op = out + ((size_t)(bq*CC + o)*NN + nq)*TT;
        const float* Sp = So[q] + o*TT;
        *(float4*)&op[0] = *(const float4*)&Sp[0];
        *(float4*)&op[4] = *(const float4*)&Sp[4];
        *(float4*)&op[8] = *(const float4*)&Sp[8];
    }
}

// ---------------------------------------------------------------------------
extern "C" void kernel_launch(void* const* d_in, const int* in_sizes, int n_in,
                              void* d_out, int out_size, void* d_ws, size_t ws_size,
                              hipStream_t stream) {
    const float* x   = (const float*)d_in[0];
    const float* adj = (const float*)d_in[1];
    const float* W   = (const float*)d_in[2];
    const float* a1  = (const float*)d_in[3];
    const float* a2  = (const float*)d_in[4];
    const float* Wg  = (const float*)d_in[5];
    const float* bg  = (const float*)d_in[6];
    const float* Wm  = (const float*)d_in[7];
    const float* bm  = (const float*)d_in[8];
    float* out = (float*)d_out;

    char* ws = (char*)d_ws;
    size_t off = 0;
    auto alloc = [&](size_t bytes) -> void* {
        void* p = ws + off;
        off += (bytes + 255) & ~(size_t)255;
        return p;
    };

    uint_t* maskbits = (uint_t*)alloc((size_t)512 * 16 * 4);                // 32 KB
    float* p1   = (float*)alloc(HH*CC * sizeof(float));
    float* p2   = (float*)alloc(HH*CC * sizeof(float));
    ushort_t* WmB = (ushort_t*)alloc((size_t)CC*3*CC * 2);                  // 24.6 KB
    ushort_t* WgB = (ushort_t*)alloc((size_t)FF*HF * 2);
    ushort_t* WtB = (ushort_t*)alloc((size_t)HH*CC*FF * 2);                 // 32 KB
    float* xT   = (float*)alloc((size_t)NNODE * CT * sizeof(float));        // 12.3 MB
    ushort_t* WhT  = (ushort_t*)alloc((size_t)NBHT * 64 * 512 * 2);         // 25.2 MB
    ushort_t* hprB = (ushort_t*)alloc((size_t)NNODE * NBT * FF * 2);        // 24.6 MB
    float* e1   = (float*)alloc((size_t)NROWS * sizeof(float));
    float* e2   = (float*)alloc((size_t)NROWS * sizeof(float));
    float* h1   = (float*)alloc((size_t)NNODE * CT * sizeof(float));        // 12.3 MB
    (void)ws_size;

    k016_setup<<<561, 256, 0, stream>>>(adj, W, a1, a2, Wm, Wg, x,
                                        maskbits, p1, p2, WmB, WgB, WtB, xT, WhT);

    // layer 1
    k2_wh_e <<<8*63,    256, 0, stream>>>(xT, WtB, p1, p2, WhT, e1, e2);
    k3_attn <<<NBHT*2,  256, 0, stream>>>(WhT, e1, e2, maskbits, hprB);
    k4_mfma <<<NNODE/4, 256, 0, stream>>>(hprB, WgB, bg, xT, h1);

    // layer 2
    k2_wh_e <<<8*63,    256, 0, stream>>>(h1, WtB, p1, p2, WhT, e1, e2);
    k3_attn <<<NBHT*2,  256, 0, stream>>>(WhT, e1, e2, maskbits, hprB);

    // fused layer-2 mix + final (both matmuls on MFMA)
    k45_fused<<<NNODE/4, 256, 0, stream>>>(hprB, WgB, bg, xT, h1, WmB, bm, out);
}

// Round 19
// 298.708 us; speedup vs baseline: 1.0206x; 1.0152x over previous
//
#include <hip/hip_runtime.h>
#include <hip/hip_bf16.h>
#include <math.h>

#define BB 8
#define CC 64
#define NN 500
#define TT 12
#define HH 4
#define FF 64
#define CT (CC*TT)      // 768
#define HF (HH*FF)      // 256
#define NBT (HH*TT)     // 48
#define NBHT (BB*NBT)   // 384
#define NROWS (BB*HH*TT*NN)  // 192000
#define NNODE (BB*NN)   // 4000
#define BSR 200         // k45 LDS row stride (ushorts)
#define KST 68          // k2 LDS B row stride (ushorts)
#define WTS 520         // k2 WT-lds t-row stride (ushorts)

typedef unsigned short ushort_t;
typedef unsigned int uint_t;
typedef __attribute__((ext_vector_type(8))) short short8;
typedef __attribute__((ext_vector_type(4))) float floatx4;

static __device__ __forceinline__ ushort_t f2bf(float v) {
    __hip_bfloat16 h = __float2bfloat16(v);
    ushort_t u;
    __builtin_memcpy(&u, &h, 2);
    return u;
}

static __device__ __forceinline__ float bf2f(ushort_t u) {
    return __uint_as_float(((uint_t)u) << 16);
}

// pack two f32 -> packed bf16 (lo = a, hi = b), RNE (hw v_cvt_pk on gfx950)
static __device__ __forceinline__ uint_t pkbf(float a, float b) {
    __hip_bfloat162 h = __float22bfloat162_rn(make_float2(a, b));
    uint_t u;
    __builtin_memcpy(&u, &h, 4);
    return u;
}

// ---------------------------------------------------------------------------
// K016: merged setup + x-transpose(->bf16) + WhT tail zero.
// Blocks [0,32):    bitmask[512][16 dwords] of (adj+I)>0.
// Blocks [32,209):  p1/p2 folds, WmB=bf16(Wm), WgB=bf16(Wg), WtB=bf16(W^T).
// Blocks [209,465): transpose x -> xB bf16 node-major [t][64c].
// Blocks [465,561): zero WhT m-tail [500,512).
// ---------------------------------------------------------------------------
__global__ __launch_bounds__(256) void k016_setup(const float* __restrict__ adj,
                                                  const float* __restrict__ W,
                                                  const float* __restrict__ a1,
                                                  const float* __restrict__ a2,
                                                  const float* __restrict__ Wm,
                                                  const float* __restrict__ Wg,
                                                  const float* __restrict__ x,
                                                  uint_t* __restrict__ maskbits,
                                                  float* __restrict__ p1,
                                                  float* __restrict__ p2,
                                                  ushort_t* __restrict__ WmB,
                                                  ushort_t* __restrict__ WgB,
                                                  ushort_t* __restrict__ WtB,
                                                  ushort_t* __restrict__ xB,
                                                  ushort_t* __restrict__ WhT) {
    __shared__ float tile[16*776];   // used by the x-transpose path only
    int blk = blockIdx.x;
    if (blk < 32) {
        int idx = blk * 256 + threadIdx.x;   // < 512*16
        int n = idx >> 4, j = idx & 15;      // dword j covers m = j*32..+31
        uint_t v = 0;
        if (n < NN) {
            int m0 = j * 32;
            for (int i = 0; i < 32; ++i) {
                int m = m0 + i;
                bool p = (m < NN) && (adj[n*NN + m] > 0.f || m == n);
                v |= (p ? 1u : 0u) << i;
            }
        }
        maskbits[idx] = v;
        return;
    }
    if (blk < 209) {
        int idx = (blk - 32) * 256 + threadIdx.x;
        if (idx < HH*CC) {
            int h = idx / CC, c = idx % CC;
            float s1 = 0.f, s2 = 0.f;
            for (int f = 0; f < FF; ++f) {
                float w = W[(h*CC + c)*FF + f];
                s1 += w * a1[h*FF + f];
                s2 += w * a2[h*FF + f];
            }
            p1[idx] = s1; p2[idx] = s2;
        }
        int j = idx - HH*CC;
        if (j >= 0 && j < CC*3*CC) {          // WmB = bf16(Wm), [o][192]
            WmB[j] = f2bf(Wm[j]);
        }
        int j2 = idx - (HH*CC + CC*3*CC);
        if (j2 >= 0 && j2 < FF*HF) {
            WgB[j2] = f2bf(Wg[j2]);
        }
        int j3 = idx - (HH*CC + CC*3*CC + FF*HF);
        if (j3 >= 0 && j3 < HH*CC*FF) {       // WtB[h][f][c] = W[h][c][f]
            int h = j3 >> 12, rem = j3 & 4095;
            int f = rem >> 6, c = rem & 63;
            WtB[j3] = f2bf(W[h*4096 + c*64 + f]);
        }
        return;
    }
    if (blk >= 465) {                         // WhT tail zero: m in [500,512)
        int row = (blk - 465) * 256 + threadIdx.x;   // < 24576 = 384*64
        uint_t* p = (uint_t*)(WhT + (size_t)row * 512 + 500);
        #pragma unroll
        for (int j = 0; j < 6; ++j) p[j] = 0;
        return;
    }
    // x-transpose: blocks 209..464 -> xblk 0..255; out bf16 [t][64c]
    int xblk = blk - 209;
    int b  = xblk >> 5;
    int n0 = (xblk & 31) * 16;
    for (int idx = threadIdx.x; idx < CC*16*TT; idx += 256) {
        int c   = idx / (16*TT);
        int rem = idx % (16*TT);
        int nl  = rem / TT;
        int t   = rem % TT;
        int n   = n0 + nl;
        if (n < NN)
            tile[nl*776 + c*TT + t] = x[((b*CC + c)*NN + n)*TT + t];
    }
    __syncthreads();
    for (int idx = threadIdx.x; idx < 16*384; idx += 256) {
        int nl = idx / 384, j = idx % 384;    // j = t*32 + c2
        int t = j >> 5, c2 = j & 31;
        int n = n0 + nl;
        if (n < NN) {
            float v0 = tile[nl*776 + (2*c2)*TT + t];
            float v1 = tile[nl*776 + (2*c2 + 1)*TT + t];
            *(uint_t*)&xB[(size_t)(b*NN + n)*CT + t*64 + 2*c2] = pkbf(v0, v1);
        }
    }
}

// ---------------------------------------------------------------------------
// K2: Wh via MFMA, writing WhT directly.  Input: bf16 node-major [t][64c]
// (xB or h1B) — no fp32 stage, no conversion pass.  Block = 8 nodes; wave =
// head.  e1/e2 fp32 accumulation from bf16 h (tiny shift, within budget).
// ---------------------------------------------------------------------------
__global__ __launch_bounds__(256) void k2_wh_e(const ushort_t* __restrict__ hinB,
                                               const ushort_t* __restrict__ WtB,
                                               const float* __restrict__ p1,
                                               const float* __restrict__ p2,
                                               ushort_t* __restrict__ WhT,
                                               float* __restrict__ e1,
                                               float* __restrict__ e2) {
    __shared__ ushort_t WTu[4*TT*WTS];    // 49920 B (per-wave transpose bufs)
    __shared__ ushort_t Bs[8][TT*KST];    // 13056 B
    int tid  = threadIdx.x;
    int wid  = tid >> 6;                  // wave = head h
    int lane = tid & 63;
    int quad = lane >> 4;
    int r    = lane & 15;
    int b    = blockIdx.x / 63;
    int nl0  = (blockIdx.x % 63) * 8;     // local m base (0..496)

    // stage bf16 rows (coalesced short8; clamp OOB tail reads)
    for (int i = tid; i < 8*TT*8; i += 256) {   // 768 short8 tasks
        int u = i / 96, rem = i % 96;
        int t = rem >> 3, c8 = rem & 7;
        int node = b*NN + nl0 + u;
        if (node > NNODE-1) node = NNODE-1;
        short8 v = *(const short8*)(hinB + (size_t)node*CT + t*64 + c8*8);
        *(short8*)&Bs[u][t*KST + c8*8] = v;
    }
    __syncthreads();

    // e1/e2 (fp32 accum from bf16 h); wave covers local nodes wid, wid+4
    {
        int t2 = lane & 15, h2 = lane >> 4;
        if (t2 < TT) {
            for (int pass = 0; pass < 2; ++pass) {
                int u  = wid + pass*4;
                int nl = nl0 + u;
                if (nl < NN) {
                    const ushort_t* Bu = Bs[u];
                    float s1 = 0.f, s2 = 0.f;
                    for (int c = 0; c < CC; ++c) {
                        float v = bf2f(Bu[t2*KST + c]);
                        s1 += v * p1[h2*CC + c];
                        s2 += v * p2[h2*CC + c];
                    }
                    int idx = ((b*HH + h2)*TT + t2)*NN + nl;
                    e1[idx] = s1;
                    e2[idx] = s2;
                }
            }
        }
    }

    ushort_t* WTl = WTu + wid*(TT*WTS);   // [12][520], wave-private

    short8 Afr[4][2];
    #pragma unroll
    for (int mt = 0; mt < 4; ++mt)
        #pragma unroll
        for (int kc = 0; kc < 2; ++kc)
            Afr[mt][kc] = *(const short8*)(WtB + wid*4096 +
                                           (mt*16 + r)*64 + kc*32 + quad*8);

    int rcl = r < TT ? r : TT-1;

    for (int u = 0; u < 8; ++u) {
        bool valid = (nl0 + u) < NN;
        floatx4 C[4];
        #pragma unroll
        for (int mt = 0; mt < 4; ++mt) C[mt] = (floatx4){0.f,0.f,0.f,0.f};
        #pragma unroll
        for (int kc = 0; kc < 2; ++kc) {
            short8 bfr = *(const short8*)&Bs[u][rcl*KST + kc*32 + quad*8];
            #pragma unroll
            for (int mt = 0; mt < 4; ++mt)
                C[mt] = __builtin_amdgcn_mfma_f32_16x16x32_bf16(Afr[mt][kc], bfr, C[mt], 0, 0, 0);
        }
        if (r < TT) {
            #pragma unroll
            for (int mt = 0; mt < 4; ++mt) {
                #pragma unroll
                for (int reg = 0; reg < 4; ++reg) {
                    int f = mt*16 + quad*4 + reg;
                    WTl[r*WTS + f*8 + u] = valid ? f2bf(C[mt][reg]) : (ushort_t)0;
                }
            }
        }
    }

    // global write: 12 t-rows; lane = f; 16B short8 covers m = nl0..nl0+7
    {
        size_t base = ((size_t)(b*NBT + wid*TT) * 64) * 512 + nl0;
        #pragma unroll
        for (int t = 0; t < TT; ++t) {
            short8 v = *(const short8*)&WTl[t*WTS + lane*8];
            *(short8*)(WhT + base + ((size_t)t*64 + lane)*512) = v;
        }
    }
}

// ---------------------------------------------------------------------------
// K3: attention PV via MFMA — EXACT R12/R14 form.  ~50 us measured, stable.
// Five attempted improvements (R8/R9/R10/R13/R15) all regressed.  FROZEN.
// ---------------------------------------------------------------------------
__global__ __launch_bounds__(256, 3) void k3_attn(const ushort_t* __restrict__ WhT,
                                                  const float* __restrict__ e1,
                                                  const float* __restrict__ e2,
                                                  const uint_t* __restrict__ maskbits,
                                                  ushort_t* __restrict__ hprB) {
    __shared__ float  e2s[512];           // 2 KB
    __shared__ uint_t mks[256*17];        // 17408 B
    int tid  = threadIdx.x;
    int wid  = tid >> 6;
    int lane = tid & 63;
    int bht  = blockIdx.x >> 1;
    int half = blockIdx.x & 1;
    int b    = bht / NBT;
    int ht   = bht % NBT;

    const float* e1p = e1 + (size_t)bht * NN;
    const float* e2p = e2 + (size_t)bht * NN;
    const ushort_t* WT = WhT + (size_t)bht * 64 * 512;
    const float L2E = 1.4426950408889634f;

    {
        int i = tid;
        e2s[i] = (i < NN) ? e2p[i] * L2E : 0.f;
        i = tid + 256;
        e2s[i] = (i < NN) ? e2p[i] * L2E : 0.f;
    }
    for (int i = tid; i < 256*16; i += 256) {
        int rl = i >> 4, dw = i & 15;
        mks[rl*17 + dw] = maskbits[(half*256 + rl)*16 + dw];
    }
    __syncthreads();

    int quad = lane >> 4;                 // 0..3
    int r    = lane & 15;                 // A-row / C-col

    const short8 ONES = {0x3F80,0x3F80,0x3F80,0x3F80,
                         0x3F80,0x3F80,0x3F80,0x3F80}; // bf16 1.0 x8

    float e1v[4];
    #pragma unroll
    for (int u = 0; u < 4; ++u) {
        int nrow = half*256 + (wid*4 + u)*16 + r;
        e1v[u] = ((nrow < NN) ? e1p[nrow] : 0.f) * L2E;
    }
    int rl0 = wid*64 + r;

    const ushort_t* WTr = WT + (size_t)r * 512;

    floatx4 C[4][4];
    floatx4 Cs[4];
    #pragma unroll
    for (int u = 0; u < 4; ++u) {
        Cs[u] = (floatx4){0.f,0.f,0.f,0.f};
        #pragma unroll
        for (int ft = 0; ft < 4; ++ft) C[u][ft] = (floatx4){0.f,0.f,0.f,0.f};
    }

    #pragma unroll
    for (int ki = 0; ki < 16; ++ki) {
        int kb = ki*32 + quad*8;

        short8 b0 = *(const short8*)(WTr + 0*8192 + kb);
        short8 b1 = *(const short8*)(WTr + 1*8192 + kb);
        short8 b2 = *(const short8*)(WTr + 2*8192 + kb);
        short8 b3 = *(const short8*)(WTr + 3*8192 + kb);

        float4 ea = *(const float4*)&e2s[kb];
        float4 eb = *(const float4*)&e2s[kb + 4];
        float ev[8] = {ea.x,ea.y,ea.z,ea.w, eb.x,eb.y,eb.z,eb.w};

        #pragma unroll
        for (int u = 0; u < 4; ++u) {
            uint_t md    = mks[(rl0 + u*16)*17 + ki];
            uint_t mbits = md >> (quad*8);
            union { uint_t w[4]; short8 s; } av;
            #pragma unroll
            for (int p = 0; p < 4; ++p) {
                float s0 = e1v[u] + ev[2*p];
                float s1 = e1v[u] + ev[2*p+1];
                float g0 = fmaxf(s0, 0.2f*s0);
                float g1 = fmaxf(s1, 0.2f*s1);
                float x0 = __builtin_amdgcn_exp2f(g0);
                float x1 = __builtin_amdgcn_exp2f(g1);
                x0 = (mbits & (1u << (2*p)))     ? x0 : 0.f;
                x1 = (mbits & (1u << (2*p + 1))) ? x1 : 0.f;
                av.w[p] = pkbf(x0, x1);
            }
            C[u][0] = __builtin_amdgcn_mfma_f32_16x16x32_bf16(av.s, b0, C[u][0], 0, 0, 0);
            C[u][1] = __builtin_amdgcn_mfma_f32_16x16x32_bf16(av.s, b1, C[u][1], 0, 0, 0);
            C[u][2] = __builtin_amdgcn_mfma_f32_16x16x32_bf16(av.s, b2, C[u][2], 0, 0, 0);
            C[u][3] = __builtin_amdgcn_mfma_f32_16x16x32_bf16(av.s, b3, C[u][3], 0, 0, 0);
            Cs[u]   = __builtin_amdgcn_mfma_f32_16x16x32_bf16(av.s, ONES, Cs[u], 0, 0, 0);
        }
    }

    #pragma unroll
    for (int u = 0; u < 4; ++u) {
        int n0 = half*256 + (wid*4 + u)*16;
        #pragma unroll
        for (int reg = 0; reg < 4; ++reg) {
            int n = n0 + quad*4 + reg;
            if (n < NN) {
                float inv = 1.0f / Cs[u][reg];
                size_t base = ((size_t)(b*NN + n)*NBT + ht)*FF;
                #pragma unroll
                for (int ft = 0; ft < 4; ++ft) {
                    float v = C[u][ft][reg] * inv;
                    v = v > 0.f ? v : __expf(v) - 1.f;
                    hprB[base + ft*16 + r] = f2bf(v);
                }
            }
        }
    }
}

// ---------------------------------------------------------------------------
// K4: head-mix 1x1 conv + residual via MFMA.  1 node per WAVE.
// Writes h1B bf16 [t][64c] with residual folded (x from xB bf16).
// ---------------------------------------------------------------------------
__global__ __launch_bounds__(256) void k4_mfma(const ushort_t* __restrict__ hprB,
                                               const ushort_t* __restrict__ WgB,
                                               const float* __restrict__ bg,
                                               const ushort_t* __restrict__ xB,
                                               ushort_t* __restrict__ h1B) {
    __shared__ float S[4][CT];            // 12288 B  ([o][t] per wave)
    int wid  = threadIdx.x >> 6;
    int lane = threadIdx.x & 63;
    int quad = lane >> 4;
    int r    = lane & 15;

    short8 Afr[4][8];
    #pragma unroll
    for (int ot = 0; ot < 4; ++ot)
        #pragma unroll
        for (int kc = 0; kc < 8; ++kc)
            Afr[ot][kc] = *(const short8*)(WgB + (size_t)(ot*16 + r)*HF + kc*32 + quad*8);

    float4 bgv[4];
    #pragma unroll
    for (int ot = 0; ot < 4; ++ot)
        bgv[ot] = *(const float4*)(bg + ot*16 + quad*4);

    int tcl = r < TT ? r : TT-1;

    int node = blockIdx.x*4 + wid;
    const ushort_t* P = hprB + (size_t)node * (NBT*FF);

    floatx4 C[4];
    #pragma unroll
    for (int ot = 0; ot < 4; ++ot) C[ot] = (floatx4){0.f,0.f,0.f,0.f};

    #pragma unroll
    for (int kc = 0; kc < 8; ++kc) {
        int k = kc*32 + quad*8;
        int h = k >> 6, f0 = k & 63;
        short8 bfr = *(const short8*)(P + (h*TT + tcl)*FF + f0);
        #pragma unroll
        for (int ot = 0; ot < 4; ++ot)
            C[ot] = __builtin_amdgcn_mfma_f32_16x16x32_bf16(Afr[ot][kc], bfr, C[ot], 0, 0, 0);
    }

    // stage v = C + bg to wave-private LDS [o][t]
    if (r < TT) {
        #pragma unroll
        for (int ot = 0; ot < 4; ++ot) {
            #pragma unroll
            for (int reg = 0; reg < 4; ++reg) {
                int o = ot*16 + quad*4 + reg;
                S[wid][o*TT + r] = C[ot][reg] + bgv[ot][reg];
            }
        }
    }
    // wave-local readback: blend residual (bf16 x), pack, coalesced stores
    {
        const ushort_t* xp = xB + (size_t)node*CT;
        ushort_t* hp = h1B + (size_t)node*CT;
        const float* Sw = S[wid];
        for (int task = lane; task < 96; task += 64) {  // (t, c-octet)
            int t = task >> 3, c8 = task & 7;
            short8 xv = *(const short8*)(xp + t*64 + c8*8);
            union { uint_t w[4]; short8 s; } ov;
            #pragma unroll
            for (int p = 0; p < 4; ++p) {
                int c0 = c8*8 + 2*p;
                float x0 = bf2f((ushort_t)xv[2*p]);
                float x1 = bf2f((ushort_t)xv[2*p+1]);
                float v0 = 0.05f*x0 + 0.95f*Sw[c0*TT + t];
                float v1 = 0.05f*x1 + 0.95f*Sw[(c0+1)*TT + t];
                ov.w[p] = pkbf(v0, v1);
            }
            *(short8*)(hp + t*64 + c8*8) = ov.s;
        }
    }
}

// ---------------------------------------------------------------------------
// K45: fused layer-2 head-mix + final mix, BOTH via MFMA.  1 node/wave.
// x, h1 staged from bf16 [t][64c] buffers by plain short8 copies; phase-1
// x-residual read from LDS section 0.
// ---------------------------------------------------------------------------
__global__ __launch_bounds__(256) void k45_fused(const ushort_t* __restrict__ hprB,
                                                 const ushort_t* __restrict__ WgB,
                                                 const float* __restrict__ bg,
                                                 const ushort_t* __restrict__ xB,
                                                 const ushort_t* __restrict__ h1B,
                                                 const ushort_t* __restrict__ WmB,
                                                 const float* __restrict__ bm,
                                                 float* __restrict__ out) {
    __shared__ ushort_t Bs[4][TT*BSR];    // 19200 B
    __shared__ float    So[4][CT];        // 12288 B
    int wid  = threadIdx.x >> 6;
    int lane = threadIdx.x & 63;
    int quad = lane >> 4;
    int r    = lane & 15;

    int node = blockIdx.x*4 + wid;
    ushort_t* Bw = Bs[wid];

    {   // stage xB, h1B -> sections 0,1 (short8 copies)
        const ushort_t* xp = xB  + (size_t)node*CT;
        const ushort_t* hp = h1B + (size_t)node*CT;
        for (int task = lane; task < 96; task += 64) {
            int t = task >> 3, c8 = task & 7;
            *(short8*)&Bw[t*BSR + c8*8]      = *(const short8*)(xp + t*64 + c8*8);
            *(short8*)&Bw[t*BSR + 64 + c8*8] = *(const short8*)(hp + t*64 + c8*8);
        }
    }

    // ---- phase 1 (k4 body): h2 via MFMA -> Bs section 2 ----
    {
        short8 Afr[4][8];
        #pragma unroll
        for (int ot = 0; ot < 4; ++ot)
            #pragma unroll
            for (int kc = 0; kc < 8; ++kc)
                Afr[ot][kc] = *(const short8*)(WgB + (size_t)(ot*16 + r)*HF + kc*32 + quad*8);
        float4 bgv[4];
        #pragma unroll
        for (int ot = 0; ot < 4; ++ot)
            bgv[ot] = *(const float4*)(bg + ot*16 + quad*4);

        int tcl = r < TT ? r : TT-1;
        const ushort_t* P = hprB + (size_t)node * (NBT*FF);

        floatx4 C[4];
        #pragma unroll
        for (int ot = 0; ot < 4; ++ot) C[ot] = (floatx4){0.f,0.f,0.f,0.f};
        #pragma unroll
        for (int kc = 0; kc < 8; ++kc) {
            int k = kc*32 + quad*8;
            int h = k >> 6, f0 = k & 63;
            short8 bfr = *(const short8*)(P + (h*TT + tcl)*FF + f0);
            #pragma unroll
            for (int ot = 0; ot < 4; ++ot)
                C[ot] = __builtin_amdgcn_mfma_f32_16x16x32_bf16(Afr[ot][kc], bfr, C[ot], 0, 0, 0);
        }

        if (r < TT) {
            #pragma unroll
            for (int ot = 0; ot < 4; ++ot) {
                #pragma unroll
                for (int rp = 0; rp < 4; rp += 2) {
                    int o = ot*16 + quad*4 + rp;
                    float v0 = C[ot][rp]   + bgv[ot][rp];
                    float v1 = C[ot][rp+1] + bgv[ot][rp+1];
                    float x0 = bf2f(Bw[r*BSR + o]);
                    float x1 = bf2f(Bw[r*BSR + o + 1]);
                    float h20 = 0.05f*x0 + 0.95f*v0;
                    float h21 = 0.05f*x1 + 0.95f*v1;
                    *(uint_t*)&Bw[r*BSR + 128 + o] = pkbf(h20, h21);
                }
            }
        }
    }

    // ---- phase 2 (k5 body): out = bm + WmB @ [x|h1|h2] via MFMA ----
    {
        short8 Am[4][6];
        #pragma unroll
        for (int ot = 0; ot < 4; ++ot)
            #pragma unroll
            for (int kc = 0; kc < 6; ++kc)
                Am[ot][kc] = *(const short8*)(WmB + (size_t)(ot*16 + r)*(3*CC) + kc*32 + quad*8);

        int trd = r < TT ? r : TT-1;      // clamp (rows 12..15 unused)
        floatx4 C2[4];
        #pragma unroll
        for (int ot = 0; ot < 4; ++ot) C2[ot] = (floatx4){0.f,0.f,0.f,0.f};
        #pragma unroll
        for (int kc = 0; kc < 6; ++kc) {
            short8 bfr = *(const short8*)&Bw[trd*BSR + kc*32 + quad*8];
            #pragma unroll
            for (int ot = 0; ot < 4; ++ot)
                C2[ot] = __builtin_amdgcn_mfma_f32_16x16x32_bf16(Am[ot][kc], bfr, C2[ot], 0, 0, 0);
        }

        if (r < TT) {
            #pragma unroll
            for (int ot = 0; ot < 4; ++ot) {
                float4 bmv = *(const float4*)(bm + ot*16 + quad*4);
                #pragma unroll
                for (int reg = 0; reg < 4; ++reg) {
                    int o = ot*16 + quad*4 + reg;
                    So[wid][o*TT + r] = C2[ot][reg] + bmv[reg];
                }
            }
        }
    }
    __syncthreads();

    {
        int o = threadIdx.x >> 2;
        int q = threadIdx.x & 3;
        int nodeq = blockIdx.x*4 + q;
        int bq = nodeq / NN, nq = nodeq % NN;
        float* op = out + ((size_t)(bq*CC + o)*NN + nq)*TT;
        const float* Sp = So[q] + o*TT;
        *(float4*)&op[0] = *(const float4*)&Sp[0];
        *(float4*)&op[4] = *(const float4*)&Sp[4];
        *(float4*)&op[8] = *(const float4*)&Sp[8];
    }
}

// ---------------------------------------------------------------------------
extern "C" void kernel_launch(void* const* d_in, const int* in_sizes, int n_in,
                              void* d_out, int out_size, void* d_ws, size_t ws_size,
                              hipStream_t stream) {
    const float* x   = (const float*)d_in[0];
    const float* adj = (const float*)d_in[1];
    const float* W   = (const float*)d_in[2];
    const float* a1  = (const float*)d_in[3];
    const float* a2  = (const float*)d_in[4];
    const float* Wg  = (const float*)d_in[5];
    const float* bg  = (const float*)d_in[6];
    const float* Wm  = (const float*)d_in[7];
    const float* bm  = (const float*)d_in[8];
    float* out = (float*)d_out;

    char* ws = (char*)d_ws;
    size_t off = 0;
    auto alloc = [&](size_t bytes) -> void* {
        void* p = ws + off;
        off += (bytes + 255) & ~(size_t)255;
        return p;
    };

    uint_t* maskbits = (uint_t*)alloc((size_t)512 * 16 * 4);                // 32 KB
    float* p1   = (float*)alloc(HH*CC * sizeof(float));
    float* p2   = (float*)alloc(HH*CC * sizeof(float));
    ushort_t* WmB = (ushort_t*)alloc((size_t)CC*3*CC * 2);                  // 24.6 KB
    ushort_t* WgB = (ushort_t*)alloc((size_t)FF*HF * 2);
    ushort_t* WtB = (ushort_t*)alloc((size_t)HH*CC*FF * 2);                 // 32 KB
    ushort_t* xB  = (ushort_t*)alloc((size_t)NNODE * CT * 2);               // 6.15 MB
    ushort_t* WhT  = (ushort_t*)alloc((size_t)NBHT * 64 * 512 * 2);         // 25.2 MB
    ushort_t* hprB = (ushort_t*)alloc((size_t)NNODE * NBT * FF * 2);        // 24.6 MB
    float* e1   = (float*)alloc((size_t)NROWS * sizeof(float));
    float* e2   = (float*)alloc((size_t)NROWS * sizeof(float));
    ushort_t* h1B = (ushort_t*)alloc((size_t)NNODE * CT * 2);               // 6.15 MB
    (void)ws_size;

    k016_setup<<<561, 256, 0, stream>>>(adj, W, a1, a2, Wm, Wg, x,
                                        maskbits, p1, p2, WmB, WgB, WtB, xB, WhT);

    // layer 1
    k2_wh_e <<<8*63,    256, 0, stream>>>(xB, WtB, p1, p2, WhT, e1, e2);
    k3_attn <<<NBHT*2,  256, 0, stream>>>(WhT, e1, e2, maskbits, hprB);
    k4_mfma <<<NNODE/4, 256, 0, stream>>>(hprB, WgB, bg, xB, h1B);

    // layer 2
    k2_wh_e <<<8*63,    256, 0, stream>>>(h1B, WtB, p1, p2, WhT, e1, e2);
    k3_attn <<<NBHT*2,  256, 0, stream>>>(WhT, e1, e2, maskbits, hprB);

    // fused layer-2 mix + final (both matmuls on MFMA)
    k45_fused<<<NNODE/4, 256, 0, stream>>>(hprB, WgB, bg, xB, h1B, WmB, bm, out);
}

// Round 20
// 289.140 us; speedup vs baseline: 1.0543x; 1.0331x over previous
//
#include <hip/hip_runtime.h>
#include <hip/hip_bf16.h>
#include <math.h>

#define BB 8
#define CC 64
#define NN 500
#define TT 12
#define HH 4
#define FF 64
#define CT (CC*TT)      // 768
#define HF (HH*FF)      // 256
#define NBT (HH*TT)     // 48
#define NBHT (BB*NBT)   // 384
#define NROWS (BB*HH*TT*NN)  // 192000
#define NNODE (BB*NN)   // 4000
#define BSR 200         // k45 LDS row stride (ushorts)
#define KST 68          // k2 LDS B row stride (ushorts)
#define WTS 520         // k2 WT-lds t-row stride (ushorts)

typedef unsigned short ushort_t;
typedef unsigned int uint_t;
typedef __attribute__((ext_vector_type(8))) short short8;
typedef __attribute__((ext_vector_type(4))) float floatx4;

static __device__ __forceinline__ ushort_t f2bf(float v) {
    __hip_bfloat16 h = __float2bfloat16(v);
    ushort_t u;
    __builtin_memcpy(&u, &h, 2);
    return u;
}

static __device__ __forceinline__ float bf2f(ushort_t u) {
    return __uint_as_float(((uint_t)u) << 16);
}

// pack two f32 -> packed bf16 (lo = a, hi = b), RNE (hw v_cvt_pk on gfx950)
static __device__ __forceinline__ uint_t pkbf(float a, float b) {
    __hip_bfloat162 h = __float22bfloat162_rn(make_float2(a, b));
    uint_t u;
    __builtin_memcpy(&u, &h, 4);
    return u;
}

// ---------------------------------------------------------------------------
// K016: merged setup + x-transpose(->bf16) + WhT tail zero.  (frozen)
// ---------------------------------------------------------------------------
__global__ __launch_bounds__(256) void k016_setup(const float* __restrict__ adj,
                                                  const float* __restrict__ W,
                                                  const float* __restrict__ a1,
                                                  const float* __restrict__ a2,
                                                  const float* __restrict__ Wm,
                                                  const float* __restrict__ Wg,
                                                  const float* __restrict__ x,
                                                  uint_t* __restrict__ maskbits,
                                                  float* __restrict__ p1,
                                                  float* __restrict__ p2,
                                                  ushort_t* __restrict__ WmB,
                                                  ushort_t* __restrict__ WgB,
                                                  ushort_t* __restrict__ WtB,
                                                  ushort_t* __restrict__ xB,
                                                  ushort_t* __restrict__ WhT) {
    __shared__ float tile[16*776];   // used by the x-transpose path only
    int blk = blockIdx.x;
    if (blk < 32) {
        int idx = blk * 256 + threadIdx.x;   // < 512*16
        int n = idx >> 4, j = idx & 15;      // dword j covers m = j*32..+31
        uint_t v = 0;
        if (n < NN) {
            int m0 = j * 32;
            for (int i = 0; i < 32; ++i) {
                int m = m0 + i;
                bool p = (m < NN) && (adj[n*NN + m] > 0.f || m == n);
                v |= (p ? 1u : 0u) << i;
            }
        }
        maskbits[idx] = v;
        return;
    }
    if (blk < 209) {
        int idx = (blk - 32) * 256 + threadIdx.x;
        if (idx < HH*CC) {
            int h = idx / CC, c = idx % CC;
            float s1 = 0.f, s2 = 0.f;
            for (int f = 0; f < FF; ++f) {
                float w = W[(h*CC + c)*FF + f];
                s1 += w * a1[h*FF + f];
                s2 += w * a2[h*FF + f];
            }
            p1[idx] = s1; p2[idx] = s2;
        }
        int j = idx - HH*CC;
        if (j >= 0 && j < CC*3*CC) {          // WmB = bf16(Wm), [o][192]
            WmB[j] = f2bf(Wm[j]);
        }
        int j2 = idx - (HH*CC + CC*3*CC);
        if (j2 >= 0 && j2 < FF*HF) {
            WgB[j2] = f2bf(Wg[j2]);
        }
        int j3 = idx - (HH*CC + CC*3*CC + FF*HF);
        if (j3 >= 0 && j3 < HH*CC*FF) {       // WtB[h][f][c] = W[h][c][f]
            int h = j3 >> 12, rem = j3 & 4095;
            int f = rem >> 6, c = rem & 63;
            WtB[j3] = f2bf(W[h*4096 + c*64 + f]);
        }
        return;
    }
    if (blk >= 465) {                         // WhT tail zero: m in [500,512)
        int row = (blk - 465) * 256 + threadIdx.x;   // < 24576 = 384*64
        uint_t* p = (uint_t*)(WhT + (size_t)row * 512 + 500);
        #pragma unroll
        for (int j = 0; j < 6; ++j) p[j] = 0;
        return;
    }
    // x-transpose: blocks 209..464 -> xblk 0..255; out bf16 [t][64c]
    int xblk = blk - 209;
    int b  = xblk >> 5;
    int n0 = (xblk & 31) * 16;
    for (int idx = threadIdx.x; idx < CC*16*TT; idx += 256) {
        int c   = idx / (16*TT);
        int rem = idx % (16*TT);
        int nl  = rem / TT;
        int t   = rem % TT;
        int n   = n0 + nl;
        if (n < NN)
            tile[nl*776 + c*TT + t] = x[((b*CC + c)*NN + n)*TT + t];
    }
    __syncthreads();
    for (int idx = threadIdx.x; idx < 16*384; idx += 256) {
        int nl = idx / 384, j = idx % 384;    // j = t*32 + c2
        int t = j >> 5, c2 = j & 31;
        int n = n0 + nl;
        if (n < NN) {
            float v0 = tile[nl*776 + (2*c2)*TT + t];
            float v1 = tile[nl*776 + (2*c2 + 1)*TT + t];
            *(uint_t*)&xB[(size_t)(b*NN + n)*CT + t*64 + 2*c2] = pkbf(v0, v1);
        }
    }
}

// ---------------------------------------------------------------------------
// K2: Wh via MFMA, writing WhT directly (layer 1; input xB).  (frozen)
// ---------------------------------------------------------------------------
__global__ __launch_bounds__(256) void k2_wh_e(const ushort_t* __restrict__ hinB,
                                               const ushort_t* __restrict__ WtB,
                                               const float* __restrict__ p1,
                                               const float* __restrict__ p2,
                                               ushort_t* __restrict__ WhT,
                                               float* __restrict__ e1,
                                               float* __restrict__ e2) {
    __shared__ ushort_t WTu[4*TT*WTS];    // 49920 B (per-wave transpose bufs)
    __shared__ ushort_t Bs[8][TT*KST];    // 13056 B
    int tid  = threadIdx.x;
    int wid  = tid >> 6;                  // wave = head h
    int lane = tid & 63;
    int quad = lane >> 4;
    int r    = lane & 15;
    int b    = blockIdx.x / 63;
    int nl0  = (blockIdx.x % 63) * 8;     // local m base (0..496)

    for (int i = tid; i < 8*TT*8; i += 256) {   // 768 short8 tasks
        int u = i / 96, rem = i % 96;
        int t = rem >> 3, c8 = rem & 7;
        int node = b*NN + nl0 + u;
        if (node > NNODE-1) node = NNODE-1;
        short8 v = *(const short8*)(hinB + (size_t)node*CT + t*64 + c8*8);
        *(short8*)&Bs[u][t*KST + c8*8] = v;
    }
    __syncthreads();

    {   // e1/e2 (fp32 accum from bf16 h)
        int t2 = lane & 15, h2 = lane >> 4;
        if (t2 < TT) {
            for (int pass = 0; pass < 2; ++pass) {
                int u  = wid + pass*4;
                int nl = nl0 + u;
                if (nl < NN) {
                    const ushort_t* Bu = Bs[u];
                    float s1 = 0.f, s2 = 0.f;
                    for (int c = 0; c < CC; ++c) {
                        float v = bf2f(Bu[t2*KST + c]);
                        s1 += v * p1[h2*CC + c];
                        s2 += v * p2[h2*CC + c];
                    }
                    int idx = ((b*HH + h2)*TT + t2)*NN + nl;
                    e1[idx] = s1;
                    e2[idx] = s2;
                }
            }
        }
    }

    ushort_t* WTl = WTu + wid*(TT*WTS);   // [12][520], wave-private

    short8 Afr[4][2];
    #pragma unroll
    for (int mt = 0; mt < 4; ++mt)
        #pragma unroll
        for (int kc = 0; kc < 2; ++kc)
            Afr[mt][kc] = *(const short8*)(WtB + wid*4096 +
                                           (mt*16 + r)*64 + kc*32 + quad*8);

    int rcl = r < TT ? r : TT-1;

    for (int u = 0; u < 8; ++u) {
        bool valid = (nl0 + u) < NN;
        floatx4 C[4];
        #pragma unroll
        for (int mt = 0; mt < 4; ++mt) C[mt] = (floatx4){0.f,0.f,0.f,0.f};
        #pragma unroll
        for (int kc = 0; kc < 2; ++kc) {
            short8 bfr = *(const short8*)&Bs[u][rcl*KST + kc*32 + quad*8];
            #pragma unroll
            for (int mt = 0; mt < 4; ++mt)
                C[mt] = __builtin_amdgcn_mfma_f32_16x16x32_bf16(Afr[mt][kc], bfr, C[mt], 0, 0, 0);
        }
        if (r < TT) {
            #pragma unroll
            for (int mt = 0; mt < 4; ++mt) {
                #pragma unroll
                for (int reg = 0; reg < 4; ++reg) {
                    int f = mt*16 + quad*4 + reg;
                    WTl[r*WTS + f*8 + u] = valid ? f2bf(C[mt][reg]) : (ushort_t)0;
                }
            }
        }
    }

    {
        size_t base = ((size_t)(b*NBT + wid*TT) * 64) * 512 + nl0;
        #pragma unroll
        for (int t = 0; t < TT; ++t) {
            short8 v = *(const short8*)&WTl[t*WTS + lane*8];
            *(short8*)(WhT + base + ((size_t)t*64 + lane)*512) = v;
        }
    }
}

// ---------------------------------------------------------------------------
// K42: FUSED layer-1 head-mix (k4 body) + layer-2 Wh/e (k2 body).
// Block = 8 nodes; stage xB -> Bs; phase A computes h1 = 0.05x + 0.95(Wg@hpr
// + bg) per node (2 nodes/wave), writing bf16 h1 in-place into Bs AND to
// h1B global (k45 needs it); barrier; phase B = k2 body verbatim on the
// LDS-resident h1.  Bit-identical numerics to the separate k4 -> k2 chain
// (same fp32 ops, same RNE pack points).
// ---------------------------------------------------------------------------
__global__ __launch_bounds__(256) void k42_fused(const ushort_t* __restrict__ hprB,
                                                 const ushort_t* __restrict__ WgB,
                                                 const float* __restrict__ bg,
                                                 const ushort_t* __restrict__ xB,
                                                 ushort_t* __restrict__ h1B,
                                                 const ushort_t* __restrict__ WtB,
                                                 const float* __restrict__ p1,
                                                 const float* __restrict__ p2,
                                                 ushort_t* __restrict__ WhT,
                                                 float* __restrict__ e1,
                                                 float* __restrict__ e2) {
    __shared__ ushort_t WTu[4*TT*WTS];    // 49920 B
    __shared__ ushort_t Bs[8][TT*KST];    // 13056 B  (total 62976 B)
    int tid  = threadIdx.x;
    int wid  = tid >> 6;
    int lane = tid & 63;
    int quad = lane >> 4;
    int r    = lane & 15;
    int b    = blockIdx.x / 63;
    int nl0  = (blockIdx.x % 63) * 8;

    // stage xB -> Bs (coalesced short8; clamp OOB tail)
    for (int i = tid; i < 8*TT*8; i += 256) {
        int u = i / 96, rem = i % 96;
        int t = rem >> 3, c8 = rem & 7;
        int node = b*NN + nl0 + u;
        if (node > NNODE-1) node = NNODE-1;
        *(short8*)&Bs[u][t*KST + c8*8] =
            *(const short8*)(xB + (size_t)node*CT + t*64 + c8*8);
    }
    __syncthreads();

    // ---- phase A (k4 body): nodes u = wid, wid+4 ----
    {
        short8 Ag[4][8];
        #pragma unroll
        for (int ot = 0; ot < 4; ++ot)
            #pragma unroll
            for (int kc = 0; kc < 8; ++kc)
                Ag[ot][kc] = *(const short8*)(WgB + (size_t)(ot*16 + r)*HF + kc*32 + quad*8);
        float4 bgv[4];
        #pragma unroll
        for (int ot = 0; ot < 4; ++ot)
            bgv[ot] = *(const float4*)(bg + ot*16 + quad*4);

        int tcl = r < TT ? r : TT-1;

        for (int p = 0; p < 2; ++p) {
            int u  = wid + p*4;
            int nl = nl0 + u;
            int node = b*NN + nl;
            int nodec = node > NNODE-1 ? NNODE-1 : node;
            const ushort_t* P = hprB + (size_t)nodec * (NBT*FF);

            floatx4 C[4];
            #pragma unroll
            for (int ot = 0; ot < 4; ++ot) C[ot] = (floatx4){0.f,0.f,0.f,0.f};
            #pragma unroll
            for (int kc = 0; kc < 8; ++kc) {
                int k = kc*32 + quad*8;
                int h = k >> 6, f0 = k & 63;
                short8 bfr = *(const short8*)(P + (h*TT + tcl)*FF + f0);
                #pragma unroll
                for (int ot = 0; ot < 4; ++ot)
                    C[ot] = __builtin_amdgcn_mfma_f32_16x16x32_bf16(Ag[ot][kc], bfr, C[ot], 0, 0, 0);
            }

            if (r < TT && nl < NN) {
                ushort_t* hp = h1B + (size_t)node*CT;
                #pragma unroll
                for (int ot = 0; ot < 4; ++ot) {
                    #pragma unroll
                    for (int rp = 0; rp < 4; rp += 2) {
                        int o = ot*16 + quad*4 + rp;      // even
                        uint_t xu = *(const uint_t*)&Bs[u][r*KST + o];
                        float x0 = bf2f((ushort_t)(xu & 0xffffu));
                        float x1 = bf2f((ushort_t)(xu >> 16));
                        float v0 = C[ot][rp]   + bgv[ot][rp];
                        float v1 = C[ot][rp+1] + bgv[ot][rp+1];
                        uint_t pv = pkbf(0.05f*x0 + 0.95f*v0,
                                         0.05f*x1 + 0.95f*v1);
                        *(uint_t*)&Bs[u][r*KST + o] = pv;   // h1 into LDS
                        *(uint_t*)&hp[r*64 + o]     = pv;   // h1B for k45
                    }
                }
            }
        }
    }
    __syncthreads();                      // Bs now holds h1 rows

    // ---- phase B (k2 body): e1/e2 + Wh MFMA + WhT transpose/store ----
    {
        int t2 = lane & 15, h2 = lane >> 4;
        if (t2 < TT) {
            for (int pass = 0; pass < 2; ++pass) {
                int u  = wid + pass*4;
                int nl = nl0 + u;
                if (nl < NN) {
                    const ushort_t* Bu = Bs[u];
                    float s1 = 0.f, s2 = 0.f;
                    for (int c = 0; c < CC; ++c) {
                        float v = bf2f(Bu[t2*KST + c]);
                        s1 += v * p1[h2*CC + c];
                        s2 += v * p2[h2*CC + c];
                    }
                    int idx = ((b*HH + h2)*TT + t2)*NN + nl;
                    e1[idx] = s1;
                    e2[idx] = s2;
                }
            }
        }
    }

    ushort_t* WTl = WTu + wid*(TT*WTS);

    short8 Afr[4][2];
    #pragma unroll
    for (int mt = 0; mt < 4; ++mt)
        #pragma unroll
        for (int kc = 0; kc < 2; ++kc)
            Afr[mt][kc] = *(const short8*)(WtB + wid*4096 +
                                           (mt*16 + r)*64 + kc*32 + quad*8);

    int rcl = r < TT ? r : TT-1;

    for (int u = 0; u < 8; ++u) {
        bool valid = (nl0 + u) < NN;
        floatx4 C[4];
        #pragma unroll
        for (int mt = 0; mt < 4; ++mt) C[mt] = (floatx4){0.f,0.f,0.f,0.f};
        #pragma unroll
        for (int kc = 0; kc < 2; ++kc) {
            short8 bfr = *(const short8*)&Bs[u][rcl*KST + kc*32 + quad*8];
            #pragma unroll
            for (int mt = 0; mt < 4; ++mt)
                C[mt] = __builtin_amdgcn_mfma_f32_16x16x32_bf16(Afr[mt][kc], bfr, C[mt], 0, 0, 0);
        }
        if (r < TT) {
            #pragma unroll
            for (int mt = 0; mt < 4; ++mt) {
                #pragma unroll
                for (int reg = 0; reg < 4; ++reg) {
                    int f = mt*16 + quad*4 + reg;
                    WTl[r*WTS + f*8 + u] = valid ? f2bf(C[mt][reg]) : (ushort_t)0;
                }
            }
        }
    }

    {
        size_t base = ((size_t)(b*NBT + wid*TT) * 64) * 512 + nl0;
        #pragma unroll
        for (int t = 0; t < TT; ++t) {
            short8 v = *(const short8*)&WTl[t*WTS + lane*8];
            *(short8*)(WhT + base + ((size_t)t*64 + lane)*512) = v;
        }
    }
}

// ---------------------------------------------------------------------------
// K3: attention PV via MFMA — EXACT R12/R14 form.  ~51 us, stable.  FROZEN.
// ---------------------------------------------------------------------------
__global__ __launch_bounds__(256, 3) void k3_attn(const ushort_t* __restrict__ WhT,
                                                  const float* __restrict__ e1,
                                                  const float* __restrict__ e2,
                                                  const uint_t* __restrict__ maskbits,
                                                  ushort_t* __restrict__ hprB) {
    __shared__ float  e2s[512];           // 2 KB
    __shared__ uint_t mks[256*17];        // 17408 B
    int tid  = threadIdx.x;
    int wid  = tid >> 6;
    int lane = tid & 63;
    int bht  = blockIdx.x >> 1;
    int half = blockIdx.x & 1;
    int b    = bht / NBT;
    int ht   = bht % NBT;

    const float* e1p = e1 + (size_t)bht * NN;
    const float* e2p = e2 + (size_t)bht * NN;
    const ushort_t* WT = WhT + (size_t)bht * 64 * 512;
    const float L2E = 1.4426950408889634f;

    {
        int i = tid;
        e2s[i] = (i < NN) ? e2p[i] * L2E : 0.f;
        i = tid + 256;
        e2s[i] = (i < NN) ? e2p[i] * L2E : 0.f;
    }
    for (int i = tid; i < 256*16; i += 256) {
        int rl = i >> 4, dw = i & 15;
        mks[rl*17 + dw] = maskbits[(half*256 + rl)*16 + dw];
    }
    __syncthreads();

    int quad = lane >> 4;                 // 0..3
    int r    = lane & 15;                 // A-row / C-col

    const short8 ONES = {0x3F80,0x3F80,0x3F80,0x3F80,
                         0x3F80,0x3F80,0x3F80,0x3F80}; // bf16 1.0 x8

    float e1v[4];
    #pragma unroll
    for (int u = 0; u < 4; ++u) {
        int nrow = half*256 + (wid*4 + u)*16 + r;
        e1v[u] = ((nrow < NN) ? e1p[nrow] : 0.f) * L2E;
    }
    int rl0 = wid*64 + r;

    const ushort_t* WTr = WT + (size_t)r * 512;

    floatx4 C[4][4];
    floatx4 Cs[4];
    #pragma unroll
    for (int u = 0; u < 4; ++u) {
        Cs[u] = (floatx4){0.f,0.f,0.f,0.f};
        #pragma unroll
        for (int ft = 0; ft < 4; ++ft) C[u][ft] = (floatx4){0.f,0.f,0.f,0.f};
    }

    #pragma unroll
    for (int ki = 0; ki < 16; ++ki) {
        int kb = ki*32 + quad*8;

        short8 b0 = *(const short8*)(WTr + 0*8192 + kb);
        short8 b1 = *(const short8*)(WTr + 1*8192 + kb);
        short8 b2 = *(const short8*)(WTr + 2*8192 + kb);
        short8 b3 = *(const short8*)(WTr + 3*8192 + kb);

        float4 ea = *(const float4*)&e2s[kb];
        float4 eb = *(const float4*)&e2s[kb + 4];
        float ev[8] = {ea.x,ea.y,ea.z,ea.w, eb.x,eb.y,eb.z,eb.w};

        #pragma unroll
        for (int u = 0; u < 4; ++u) {
            uint_t md    = mks[(rl0 + u*16)*17 + ki];
            uint_t mbits = md >> (quad*8);
            union { uint_t w[4]; short8 s; } av;
            #pragma unroll
            for (int p = 0; p < 4; ++p) {
                float s0 = e1v[u] + ev[2*p];
                float s1 = e1v[u] + ev[2*p+1];
                float g0 = fmaxf(s0, 0.2f*s0);
                float g1 = fmaxf(s1, 0.2f*s1);
                float x0 = __builtin_amdgcn_exp2f(g0);
                float x1 = __builtin_amdgcn_exp2f(g1);
                x0 = (mbits & (1u << (2*p)))     ? x0 : 0.f;
                x1 = (mbits & (1u << (2*p + 1))) ? x1 : 0.f;
                av.w[p] = pkbf(x0, x1);
            }
            C[u][0] = __builtin_amdgcn_mfma_f32_16x16x32_bf16(av.s, b0, C[u][0], 0, 0, 0);
            C[u][1] = __builtin_amdgcn_mfma_f32_16x16x32_bf16(av.s, b1, C[u][1], 0, 0, 0);
            C[u][2] = __builtin_amdgcn_mfma_f32_16x16x32_bf16(av.s, b2, C[u][2], 0, 0, 0);
            C[u][3] = __builtin_amdgcn_mfma_f32_16x16x32_bf16(av.s, b3, C[u][3], 0, 0, 0);
            Cs[u]   = __builtin_amdgcn_mfma_f32_16x16x32_bf16(av.s, ONES, Cs[u], 0, 0, 0);
        }
    }

    #pragma unroll
    for (int u = 0; u < 4; ++u) {
        int n0 = half*256 + (wid*4 + u)*16;
        #pragma unroll
        for (int reg = 0; reg < 4; ++reg) {
            int n = n0 + quad*4 + reg;
            if (n < NN) {
                float inv = 1.0f / Cs[u][reg];
                size_t base = ((size_t)(b*NN + n)*NBT + ht)*FF;
                #pragma unroll
                for (int ft = 0; ft < 4; ++ft) {
                    float v = C[u][ft][reg] * inv;
                    v = v > 0.f ? v : __expf(v) - 1.f;
                    hprB[base + ft*16 + r] = f2bf(v);
                }
            }
        }
    }
}

// ---------------------------------------------------------------------------
// K45: fused layer-2 head-mix + final mix, BOTH via MFMA.  1 node/wave.
// (frozen from R19)
// ---------------------------------------------------------------------------
__global__ __launch_bounds__(256) void k45_fused(const ushort_t* __restrict__ hprB,
                                                 const ushort_t* __restrict__ WgB,
                                                 const float* __restrict__ bg,
                                                 const ushort_t* __restrict__ xB,
                                                 const ushort_t* __restrict__ h1B,
                                                 const ushort_t* __restrict__ WmB,
                                                 const float* __restrict__ bm,
                                                 float* __restrict__ out) {
    __shared__ ushort_t Bs[4][TT*BSR];    // 19200 B
    __shared__ float    So[4][CT];        // 12288 B
    int wid  = threadIdx.x >> 6;
    int lane = threadIdx.x & 63;
    int quad = lane >> 4;
    int r    = lane & 15;

    int node = blockIdx.x*4 + wid;
    ushort_t* Bw = Bs[wid];

    {   // stage xB, h1B -> sections 0,1 (short8 copies)
        const ushort_t* xp = xB  + (size_t)node*CT;
        const ushort_t* hp = h1B + (size_t)node*CT;
        for (int task = lane; task < 96; task += 64) {
            int t = task >> 3, c8 = task & 7;
            *(short8*)&Bw[t*BSR + c8*8]      = *(const short8*)(xp + t*64 + c8*8);
            *(short8*)&Bw[t*BSR + 64 + c8*8] = *(const short8*)(hp + t*64 + c8*8);
        }
    }

    // ---- phase 1 (k4 body): h2 via MFMA -> Bs section 2 ----
    {
        short8 Afr[4][8];
        #pragma unroll
        for (int ot = 0; ot < 4; ++ot)
            #pragma unroll
            for (int kc = 0; kc < 8; ++kc)
                Afr[ot][kc] = *(const short8*)(WgB + (size_t)(ot*16 + r)*HF + kc*32 + quad*8);
        float4 bgv[4];
        #pragma unroll
        for (int ot = 0; ot < 4; ++ot)
            bgv[ot] = *(const float4*)(bg + ot*16 + quad*4);

        int tcl = r < TT ? r : TT-1;
        const ushort_t* P = hprB + (size_t)node * (NBT*FF);

        floatx4 C[4];
        #pragma unroll
        for (int ot = 0; ot < 4; ++ot) C[ot] = (floatx4){0.f,0.f,0.f,0.f};
        #pragma unroll
        for (int kc = 0; kc < 8; ++kc) {
            int k = kc*32 + quad*8;
            int h = k >> 6, f0 = k & 63;
            short8 bfr = *(const short8*)(P + (h*TT + tcl)*FF + f0);
            #pragma unroll
            for (int ot = 0; ot < 4; ++ot)
                C[ot] = __builtin_amdgcn_mfma_f32_16x16x32_bf16(Afr[ot][kc], bfr, C[ot], 0, 0, 0);
        }

        if (r < TT) {
            #pragma unroll
            for (int ot = 0; ot < 4; ++ot) {
                #pragma unroll
                for (int rp = 0; rp < 4; rp += 2) {
                    int o = ot*16 + quad*4 + rp;
                    float v0 = C[ot][rp]   + bgv[ot][rp];
                    float v1 = C[ot][rp+1] + bgv[ot][rp+1];
                    float x0 = bf2f(Bw[r*BSR + o]);
                    float x1 = bf2f(Bw[r*BSR + o + 1]);
                    float h20 = 0.05f*x0 + 0.95f*v0;
                    float h21 = 0.05f*x1 + 0.95f*v1;
                    *(uint_t*)&Bw[r*BSR + 128 + o] = pkbf(h20, h21);
                }
            }
        }
    }

    // ---- phase 2 (k5 body): out = bm + WmB @ [x|h1|h2] via MFMA ----
    {
        short8 Am[4][6];
        #pragma unroll
        for (int ot = 0; ot < 4; ++ot)
            #pragma unroll
            for (int kc = 0; kc < 6; ++kc)
                Am[ot][kc] = *(const short8*)(WmB + (size_t)(ot*16 + r)*(3*CC) + kc*32 + quad*8);

        int trd = r < TT ? r : TT-1;      // clamp (rows 12..15 unused)
        floatx4 C2[4];
        #pragma unroll
        for (int ot = 0; ot < 4; ++ot) C2[ot] = (floatx4){0.f,0.f,0.f,0.f};
        #pragma unroll
        for (int kc = 0; kc < 6; ++kc) {
            short8 bfr = *(const short8*)&Bw[trd*BSR + kc*32 + quad*8];
            #pragma unroll
            for (int ot = 0; ot < 4; ++ot)
                C2[ot] = __builtin_amdgcn_mfma_f32_16x16x32_bf16(Am[ot][kc], bfr, C2[ot], 0, 0, 0);
        }

        if (r < TT) {
            #pragma unroll
            for (int ot = 0; ot < 4; ++ot) {
                float4 bmv = *(const float4*)(bm + ot*16 + quad*4);
                #pragma unroll
                for (int reg = 0; reg < 4; ++reg) {
                    int o = ot*16 + quad*4 + reg;
                    So[wid][o*TT + r] = C2[ot][reg] + bmv[reg];
                }
            }
        }
    }
    __syncthreads();

    {
        int o = threadIdx.x >> 2;
        int q = threadIdx.x & 3;
        int nodeq = blockIdx.x*4 + q;
        int bq = nodeq / NN, nq = nodeq % NN;
        float* op = out + ((size_t)(bq*CC + o)*NN + nq)*TT;
        const float* Sp = So[q] + o*TT;
        *(float4*)&op[0] = *(const float4*)&Sp[0];
        *(float4*)&op[4] = *(const float4*)&Sp[4];
        *(float4*)&op[8] = *(const float4*)&Sp[8];
    }
}

// ---------------------------------------------------------------------------
extern "C" void kernel_launch(void* const* d_in, const int* in_sizes, int n_in,
                              void* d_out, int out_size, void* d_ws, size_t ws_size,
                              hipStream_t stream) {
    const float* x   = (const float*)d_in[0];
    const float* adj = (const float*)d_in[1];
    const float* W   = (const float*)d_in[2];
    const float* a1  = (const float*)d_in[3];
    const float* a2  = (const float*)d_in[4];
    const float* Wg  = (const float*)d_in[5];
    const float* bg  = (const float*)d_in[6];
    const float* Wm  = (const float*)d_in[7];
    const float* bm  = (const float*)d_in[8];
    float* out = (float*)d_out;

    char* ws = (char*)d_ws;
    size_t off = 0;
    auto alloc = [&](size_t bytes) -> void* {
        void* p = ws + off;
        off += (bytes + 255) & ~(size_t)255;
        return p;
    };

    uint_t* maskbits = (uint_t*)alloc((size_t)512 * 16 * 4);                // 32 KB
    float* p1   = (float*)alloc(HH*CC * sizeof(float));
    float* p2   = (float*)alloc(HH*CC * sizeof(float));
    ushort_t* WmB = (ushort_t*)alloc((size_t)CC*3*CC * 2);                  // 24.6 KB
    ushort_t* WgB = (ushort_t*)alloc((size_t)FF*HF * 2);
    ushort_t* WtB = (ushort_t*)alloc((size_t)HH*CC*FF * 2);                 // 32 KB
    ushort_t* xB  = (ushort_t*)alloc((size_t)NNODE * CT * 2);               // 6.15 MB
    ushort_t* WhT  = (ushort_t*)alloc((size_t)NBHT * 64 * 512 * 2);         // 25.2 MB
    ushort_t* hprB = (ushort_t*)alloc((size_t)NNODE * NBT * FF * 2);        // 24.6 MB
    float* e1   = (float*)alloc((size_t)NROWS * sizeof(float));
    float* e2   = (float*)alloc((size_t)NROWS * sizeof(float));
    ushort_t* h1B = (ushort_t*)alloc((size_t)NNODE * CT * 2);               // 6.15 MB
    (void)ws_size;

    k016_setup<<<561, 256, 0, stream>>>(adj, W, a1, a2, Wm, Wg, x,
                                        maskbits, p1, p2, WmB, WgB, WtB, xB, WhT);

    // layer 1
    k2_wh_e <<<8*63,    256, 0, stream>>>(xB, WtB, p1, p2, WhT, e1, e2);
    k3_attn <<<NBHT*2,  256, 0, stream>>>(WhT, e1, e2, maskbits, hprB);

    // fused: layer-1 head-mix + layer-2 Wh/e  (k4 + k2 in one launch)
    k42_fused<<<8*63,   256, 0, stream>>>(hprB, WgB, bg, xB, h1B,
                                          WtB, p1, p2, WhT, e1, e2);

    // layer 2 attention
    k3_attn <<<NBHT*2,  256, 0, stream>>>(WhT, e1, e2, maskbits, hprB);

    // fused layer-2 mix + final
    k45_fused<<<NNODE/4, 256, 0, stream>>>(hprB, WgB, bg, xB, h1B, WmB, bm, out);
}